// Round 4
// baseline (22838.010 us; speedup 1.0000x reference)
//
#include <hip/hip_runtime.h>
#include <math.h>

typedef unsigned short u16;
typedef unsigned int   u32;

// ---------------- problem constants ----------------------------------------
// B=8, Cin=3, H=W=256, E=64, HID=128, Cout=1, SUB=16, WS=4, NH=4, dh=16, L=4
// tokens: 2048 = 128 windows x 16; token tensor [n][256 px][64 ch] (ch fastest)
#define NTOK  2048
#define TOKSZ 16384ull                  // 256*64 elems per token
#define DSZ   (2048ull*16384ull)        // elems in full token tensor
#define OSL   (2048ull*256ull*16ull)    // one head-slab [n][px][16]

__device__ __forceinline__ float bf2f(u16 b) { return __uint_as_float(((u32)b) << 16); }
__device__ __forceinline__ u16 f2bf(float f) {
    u32 u = __float_as_uint(f);
    u += 0x7FFFu + ((u >> 16) & 1u);    // RNE
    return (u16)(u >> 16);
}
__device__ __forceinline__ float gelu_f(float x) {
    return 0.5f * x * (1.0f + erff(x * 0.70710678118654752440f));
}
// shifted-view token n (grid g) <-> original token at grid g+2 (mod 16), both axes
__device__ __forceinline__ int shift_tok(int n) {
    int w = n >> 4, s = n & 15;
    int b = w >> 4, wy = (w >> 2) & 3, wx = w & 3;
    int ty = s >> 2, tx = s & 3;
    int gy = ((wy << 2) + ty + 2) & 15;
    int gx = ((wx << 2) + tx + 2) & 15;
    int w2 = (b << 4) + ((gy >> 2) << 2) + (gx >> 2);
    int s2 = ((gy & 3) << 2) + (gx & 3);
    return (w2 << 4) + s2;
}

// ---------------- dtype detection ------------------------------------------
// Read inp_W1 (640 elems, >=1280 bytes either dtype) as bf16 bits. Real bf16
// weights are 0.02*N(0,1) => |x| < 1 always. fp32-backed memory yields random
// low-half bf16s => some |x|>1e3 or NaN with certainty. flag: 1 = fp32 buffers.
__global__ void detect_kernel(const u16* __restrict__ w1, int* __restrict__ flag) {
    int t = threadIdx.x, bad = 0;
    for (int i = t; i < 640; i += 64) {
        float ax = fabsf(bf2f(w1[i]));
        if (!(ax < 1e3f)) bad = 1;      // catches huge and NaN
    }
    unsigned long long m = __ballot(bad);
    if (t == 0) *flag = (m != 0ull) ? 1 : 0;
}

// ---------------- weights -> fp32 workspace --------------------------------
#define NWT 20
struct WArgs { const void* src[NWT]; int off[NWT + 1]; };

__global__ __launch_bounds__(256)
void cvt_weights(WArgs a, const int* __restrict__ flag, float* __restrict__ wbuf) {
    int t = blockIdx.x * 256 + threadIdx.x;
    if (t >= a.off[NWT]) return;
    int s = 0;
    while (a.off[s + 1] <= t) ++s;
    int idx = t - a.off[s];
    wbuf[t] = (*flag) ? ((const float*)a.src[s])[idx]
                      : bf2f(((const u16*)a.src[s])[idx]);
}

// ---------------- input embed: (y,x,v0,v1,v2) -> 128(gelu) -> 64 -----------
__global__ __launch_bounds__(256)
void embed_kernel(const void* __restrict__ vin, const int* __restrict__ flag,
                  const float* __restrict__ W1, const float* __restrict__ b1,
                  const float* __restrict__ W2, const float* __restrict__ b2,
                  const int* __restrict__ pdsy, const int* __restrict__ pdsx,
                  float* __restrict__ d) {
    int n = blockIdx.x, p = threadIdx.x;
    int w = n >> 4, s = n & 15;
    int b = w >> 4, wy = (w >> 2) & 3, wx = w & 3;
    int ty = s >> 2, tx = s & 3;
    int y = ((wy << 2) + ty) * 16 + (p >> 4);
    int x = ((wx << 2) + tx) * 16 + (p & 15);
    float sy = (float)pdsy[0] * (1.0f / 256.0f);
    float sx = (float)pdsx[0] * (1.0f / 256.0f);
    int fl = *flag;

    float in[5];
    in[0] = ((float)y + 0.5f) * sy;
    in[1] = ((float)x + 0.5f) * sx;
    size_t pix = (size_t)b * 3 * 65536 + (size_t)y * 256 + (size_t)x;
    #pragma unroll
    for (int c = 0; c < 3; ++c)
        in[2 + c] = fl ? ((const float*)vin)[pix + (size_t)c * 65536]
                       : bf2f(((const u16*)vin)[pix + (size_t)c * 65536]);

    float acc[64];
    #pragma unroll
    for (int e = 0; e < 64; ++e) acc[e] = b2[e];
    for (int hid = 0; hid < 128; ++hid) {
        float h = b1[hid];
        #pragma unroll
        for (int c = 0; c < 5; ++c) h = fmaf(W1[hid * 5 + c], in[c], h);
        float g = gelu_f(h);
        #pragma unroll
        for (int e = 0; e < 64; ++e) acc[e] = fmaf(W2[e * 128 + hid], g, acc[e]);
    }
    float* dp = d + (size_t)n * TOKSZ + (size_t)p * 64;
    #pragma unroll
    for (int e = 0; e < 64; ++e) dp[e] = acc[e];
}

// ---------------- InstanceNorm -> bf16 xhat --------------------------------
__global__ __launch_bounds__(256)
void norm_xhat(const float* __restrict__ d, u16* __restrict__ xhat) {
    int n = blockIdx.x, t = threadIdx.x;
    int c = t & 63, qdr = t >> 6;
    const float* dp0 = d + (size_t)n * TOKSZ + qdr * 4096 + c;
    float s = 0.f, q = 0.f;
    #pragma unroll 8
    for (int pp = 0; pp < 64; ++pp) {
        float x = dp0[pp * 64];
        s += x; q = fmaf(x, x, q);
    }
    __shared__ float red[2][4][64];
    __shared__ float mu[64], rs[64];
    red[0][qdr][c] = s; red[1][qdr][c] = q;
    __syncthreads();
    if (t < 64) {
        float ss = red[0][0][t] + red[0][1][t] + red[0][2][t] + red[0][3][t];
        float qq = red[1][0][t] + red[1][1][t] + red[1][2][t] + red[1][3][t];
        float m = ss * (1.0f / 256.0f);
        float var = qq * (1.0f / 256.0f) - m * m;
        mu[t] = m; rs[t] = rsqrtf(var + 1e-5f);
    }
    __syncthreads();
    const float4* dp4 = (const float4*)(d + (size_t)n * TOKSZ + (size_t)t * 64);
    u32* xo = (u32*)(xhat + (size_t)n * TOKSZ + (size_t)t * 64);
    #pragma unroll
    for (int c2 = 0; c2 < 16; ++c2) {
        float4 x = dp4[c2];
        int cb = c2 * 4;
        u32 w0 = (u32)f2bf((x.x - mu[cb])     * rs[cb])
               | ((u32)f2bf((x.y - mu[cb + 1]) * rs[cb + 1]) << 16);
        u32 w1 = (u32)f2bf((x.z - mu[cb + 2]) * rs[cb + 2])
               | ((u32)f2bf((x.w - mu[cb + 3]) * rs[cb + 3]) << 16);
        xo[c2 * 2] = w0; xo[c2 * 2 + 1] = w1;
    }
}

#define UNPACK8(xb, x0,x1,x2,x3,x4,x5,x6,x7)                      \
    float x0 = __uint_as_float(xb.x << 16);                       \
    float x1 = __uint_as_float(xb.x & 0xFFFF0000u);               \
    float x2 = __uint_as_float(xb.y << 16);                       \
    float x3 = __uint_as_float(xb.y & 0xFFFF0000u);               \
    float x4 = __uint_as_float(xb.z << 16);                       \
    float x5 = __uint_as_float(xb.z & 0xFFFF0000u);               \
    float x6 = __uint_as_float(xb.w << 16);                       \
    float x7 = __uint_as_float(xb.w & 0xFFFF0000u);

// ---------------- fused q,k projection + scores + softmax ------------------
__global__ __launch_bounds__(256)
void scores_fused(const u16* __restrict__ xhat,
                  const float* __restrict__ Wq, const float* __restrict__ bq,
                  const float* __restrict__ Wk, const float* __restrict__ bk,
                  int shifted, float* __restrict__ A) {
    int w = blockIdx.x, h = blockIdx.y, t = threadIdx.x;
    __shared__ __align__(16) float qs[16 * 140];
    __shared__ __align__(16) float ks[16 * 140];
    __shared__ int nis[16];
    if (t < 16) { int n = w * 16 + t; nis[t] = shifted ? shift_tok(n) : n; }
    __syncthreads();
    int i = t >> 4, j = t & 15;
    int sel = t >> 7, tokq = (t >> 3) & 15, pq = t & 7;
    const float* Wp = sel ? Wk : Wq;
    const float* bp = sel ? bk : bq;
    float acc = 0.f;

    for (int ch = 0; ch < 32; ++ch) {
        float qacc[16];
        #pragma unroll
        for (int c2 = 0; c2 < 16; ++c2) qacc[c2] = bp[h * 16 + c2];
        const uint4* xr = (const uint4*)(xhat + (size_t)nis[tokq] * TOKSZ
                                              + (size_t)(ch * 8 + pq) * 64);
        #pragma unroll
        for (int c8 = 0; c8 < 8; ++c8) {
            uint4 xb = xr[c8];
            UNPACK8(xb, x0,x1,x2,x3,x4,x5,x6,x7)
            #pragma unroll
            for (int c2 = 0; c2 < 16; ++c2) {
                const float* wr = Wp + (h * 16 + c2) * 64 + c8 * 8;
                qacc[c2] = fmaf(wr[0], x0, qacc[c2]);
                qacc[c2] = fmaf(wr[1], x1, qacc[c2]);
                qacc[c2] = fmaf(wr[2], x2, qacc[c2]);
                qacc[c2] = fmaf(wr[3], x3, qacc[c2]);
                qacc[c2] = fmaf(wr[4], x4, qacc[c2]);
                qacc[c2] = fmaf(wr[5], x5, qacc[c2]);
                qacc[c2] = fmaf(wr[6], x6, qacc[c2]);
                qacc[c2] = fmaf(wr[7], x7, qacc[c2]);
            }
        }
        __syncthreads();   // previous dot finished reading qs/ks
        float* dst = (sel ? ks : qs) + tokq * 140 + pq * 16;
        #pragma unroll
        for (int c2 = 0; c2 < 16; ++c2) dst[c2] = qacc[c2];
        __syncthreads();
        const float4* qi = (const float4*)(qs + i * 140);
        const float4* kj = (const float4*)(ks + j * 140);
        #pragma unroll 8
        for (int cp = 0; cp < 32; ++cp) {
            float4 a = qi[cp], b = kj[cp];
            acc += a.x * b.x + a.y * b.y + a.z * b.z + a.w * b.w;
        }
    }
    float sc = acc * (1.0f / 1024.0f);
    float m = sc;
    #pragma unroll
    for (int off = 1; off < 16; off <<= 1) m = fmaxf(m, __shfl_xor(m, off, 16));
    float e = expf(sc - m);
    float ssum = e;
    #pragma unroll
    for (int off = 1; off < 16; off <<= 1) ssum += __shfl_xor(ssum, off, 16);
    A[((size_t)(w * 4 + h) * 16 + i) * 16 + j] = e / ssum;
}

// ---------------- fused v projection + o = A@v (2 heads / launch) ----------
__global__ __launch_bounds__(256)
void av_fused(const u16* __restrict__ xhat,
              const float* __restrict__ Wv, const float* __restrict__ bv,
              const float* __restrict__ A, int shifted, int hbase,
              u16* __restrict__ o) {
    int w = blockIdx.x, hh = hbase + blockIdx.y, t = threadIdx.x;
    __shared__ __align__(16) float vs[16 * 140];
    __shared__ float As[256];
    __shared__ int nis[16];
    if (t < 16) { int n = w * 16 + t; nis[t] = shifted ? shift_tok(n) : n; }
    As[t] = A[(size_t)(w * 4 + hh) * 256 + t];
    __syncthreads();
    u16* oslab = o + (size_t)blockIdx.y * OSL;
    int half = t >> 7, tokv = (t >> 3) & 15, pv = t & 7;

    for (int ch = 0; ch < 32; ++ch) {
        float vacc[8];
        #pragma unroll
        for (int c2 = 0; c2 < 8; ++c2) vacc[c2] = bv[hh * 16 + half * 8 + c2];
        const uint4* xr = (const uint4*)(xhat + (size_t)nis[tokv] * TOKSZ
                                              + (size_t)(ch * 8 + pv) * 64);
        #pragma unroll
        for (int c8 = 0; c8 < 8; ++c8) {
            uint4 xb = xr[c8];
            UNPACK8(xb, x0,x1,x2,x3,x4,x5,x6,x7)
            #pragma unroll
            for (int c2 = 0; c2 < 8; ++c2) {
                const float* wr = Wv + (hh * 16 + half * 8 + c2) * 64 + c8 * 8;
                vacc[c2] = fmaf(wr[0], x0, vacc[c2]);
                vacc[c2] = fmaf(wr[1], x1, vacc[c2]);
                vacc[c2] = fmaf(wr[2], x2, vacc[c2]);
                vacc[c2] = fmaf(wr[3], x3, vacc[c2]);
                vacc[c2] = fmaf(wr[4], x4, vacc[c2]);
                vacc[c2] = fmaf(wr[5], x5, vacc[c2]);
                vacc[c2] = fmaf(wr[6], x6, vacc[c2]);
                vacc[c2] = fmaf(wr[7], x7, vacc[c2]);
            }
        }
        __syncthreads();   // previous AV finished reading vs
        float* dst = vs + tokv * 140 + pv * 16 + half * 8;
        #pragma unroll
        for (int c2 = 0; c2 < 8; ++c2) dst[c2] = vacc[c2];
        __syncthreads();
        #pragma unroll
        for (int r = 0; r < 8; ++r) {
            int id = r * 256 + t;
            int c2 = id & 15, pp = (id >> 4) & 7, ii = id >> 7;
            float a = 0.f;
            #pragma unroll
            for (int jj = 0; jj < 16; ++jj)
                a = fmaf(As[ii * 16 + jj], vs[jj * 140 + pp * 16 + c2], a);
            oslab[(size_t)(w * 16 + ii) * 4096 + (size_t)(ch * 8 + pp) * 16 + c2] = f2bf(a);
        }
    }
}

// ---------------- Wo projection (2 heads) + residual accumulate ------------
template<bool SOUT>
__global__ __launch_bounds__(256)
void wo_accum(const u16* __restrict__ o, int h0,
              const float* __restrict__ Wo, const float* __restrict__ bo,
              float* __restrict__ dres) {
    int n = blockIdx.x, p = threadIdx.x;
    int no = SOUT ? shift_tok(n) : n;
    float acc[64];
    if (h0 == 0) {
        #pragma unroll
        for (int e = 0; e < 64; ++e) acc[e] = bo[e];
    } else {
        #pragma unroll
        for (int e = 0; e < 64; ++e) acc[e] = 0.f;
    }
    #pragma unroll
    for (int hh = 0; hh < 2; ++hh) {
        const uint4* op4 = (const uint4*)(o + (size_t)hh * OSL + (size_t)n * 4096 + p * 16);
        float xv[16];
        {
            uint4 xb = op4[0];
            UNPACK8(xb, x0,x1,x2,x3,x4,x5,x6,x7)
            xv[0]=x0; xv[1]=x1; xv[2]=x2; xv[3]=x3; xv[4]=x4; xv[5]=x5; xv[6]=x6; xv[7]=x7;
        }
        {
            uint4 xb = op4[1];
            UNPACK8(xb, x0,x1,x2,x3,x4,x5,x6,x7)
            xv[8]=x0; xv[9]=x1; xv[10]=x2; xv[11]=x3; xv[12]=x4; xv[13]=x5; xv[14]=x6; xv[15]=x7;
        }
        #pragma unroll
        for (int c2 = 0; c2 < 16; ++c2) {
            int c = (h0 + hh) * 16 + c2;
            #pragma unroll
            for (int e = 0; e < 64; ++e) acc[e] = fmaf(Wo[e * 64 + c], xv[c2], acc[e]);
        }
    }
    float* dp = dres + (size_t)no * TOKSZ + (size_t)p * 64;
    #pragma unroll
    for (int e = 0; e < 64; ++e) dp[e] += acc[e];
}

// ---------------- fused MLP: d += W2 gelu(W1 xhat + b1) + b2 ---------------
__global__ __launch_bounds__(256)
void mlp_fused(float* __restrict__ dres, const u16* __restrict__ xhat,
               const float* __restrict__ W1, const float* __restrict__ b1,
               const float* __restrict__ W2, const float* __restrict__ b2) {
    int n = blockIdx.x, p = threadIdx.x;
    float xh[64];
    const uint4* xr = (const uint4*)(xhat + (size_t)n * TOKSZ + (size_t)p * 64);
    #pragma unroll
    for (int c8 = 0; c8 < 8; ++c8) {
        uint4 xb = xr[c8];
        UNPACK8(xb, x0,x1,x2,x3,x4,x5,x6,x7)
        xh[c8*8+0]=x0; xh[c8*8+1]=x1; xh[c8*8+2]=x2; xh[c8*8+3]=x3;
        xh[c8*8+4]=x4; xh[c8*8+5]=x5; xh[c8*8+6]=x6; xh[c8*8+7]=x7;
    }
    float hb[64];
    for (int c2 = 0; c2 < 64; ++c2) {
        float a = b1[c2];
        #pragma unroll
        for (int c = 0; c < 64; ++c) a = fmaf(W1[c2 * 64 + c], xh[c], a);
        hb[c2] = gelu_f(a);
    }
    float* dp = dres + (size_t)n * TOKSZ + (size_t)p * 64;
    for (int e = 0; e < 64; ++e) {
        float a = b2[e];
        #pragma unroll
        for (int c2 = 0; c2 < 64; ++c2) a = fmaf(W2[e * 64 + c2], hb[c2], a);
        dp[e] += a;
    }
}

// ---------------- output MLP: 64 -> 128(gelu) -> 1 -------------------------
__global__ __launch_bounds__(256)
void out_mlp(const float* __restrict__ d,
             const float* __restrict__ W1, const float* __restrict__ b1,
             const float* __restrict__ W2, const float* __restrict__ b2,
             void* __restrict__ out, const int* __restrict__ flag) {
    int n = blockIdx.x, p = threadIdx.x;
    const float* dp = d + (size_t)n * TOKSZ + (size_t)p * 64;
    float xr[64];
    #pragma unroll
    for (int e = 0; e < 64; ++e) xr[e] = dp[e];
    float acc = b2[0];
    for (int hid = 0; hid < 128; ++hid) {
        float h = b1[hid];
        #pragma unroll
        for (int e = 0; e < 64; ++e) h = fmaf(W1[hid * 64 + e], xr[e], h);
        acc = fmaf(W2[hid], gelu_f(h), acc);
    }
    int w = n >> 4, s = n & 15;
    int b = w >> 4, wy = (w >> 2) & 3, wx = w & 3;
    int ty = s >> 2, tx = s & 3;
    int y = ((wy << 2) + ty) * 16 + (p >> 4);
    int x = ((wx << 2) + tx) * 16 + (p & 15);
    size_t oi = (size_t)b * 65536 + (size_t)y * 256 + (size_t)x;
    if (*flag) ((float*)out)[oi] = acc;
    else       ((u16*)out)[oi] = f2bf(acc);
}

// ---------------- host launch ----------------------------------------------
extern "C" void kernel_launch(void* const* d_in, const int* in_sizes, int n_in,
                              void* d_out, int out_size, void* d_ws, size_t ws_size,
                              hipStream_t stream) {
    (void)n_in; (void)out_size; (void)ws_size;
    const int* pdsy = (const int*)d_in[21];
    const int* pdsx = (const int*)d_in[22];

    // workspace: bufd f32 | xhat bf16 | oslab bf16 x2 | A f32 | wbuf f32 | flag
    char* wsb = (char*)d_ws;
    float* bufd  = (float*)wsb;                                  // 128 MiB
    u16*   xhat  = (u16*)(wsb + DSZ * 4);                        // 64 MiB
    u16*   oslab = (u16*)(wsb + DSZ * 4 + DSZ * 2);              // 32 MiB
    float* A     = (float*)(wsb + DSZ * 4 + DSZ * 2 + 2 * OSL * 2);
    float* wbuf  = A + 131072;
    int*   flag  = (int*)(wbuf + 131072);

    WArgs wa;
    int off[NWT + 1]; off[0] = 0;
    for (int i = 0; i < NWT; ++i) {
        wa.src[i] = d_in[i + 1];
        off[i + 1] = off[i] + in_sizes[i + 1];
        wa.off[i] = off[i];
    }
    wa.off[NWT] = off[NWT];

    detect_kernel<<<1, 64, 0, stream>>>((const u16*)d_in[1], flag);
    cvt_weights<<<(off[NWT] + 255) / 256, 256, 0, stream>>>(wa, flag, wbuf);

    const float* f_inpW1 = wbuf + off[0];
    const float* f_inpb1 = wbuf + off[1];
    const float* f_inpW2 = wbuf + off[2];
    const float* f_inpb2 = wbuf + off[3];
    const float* f_Wq = wbuf + off[4];   const float* f_bq = wbuf + off[5];
    const float* f_Wk = wbuf + off[6];   const float* f_bk = wbuf + off[7];
    const float* f_Wv = wbuf + off[8];   const float* f_bv = wbuf + off[9];
    const float* f_Wo = wbuf + off[10];  const float* f_bo = wbuf + off[11];
    const float* f_mW1 = wbuf + off[12]; const float* f_mb1 = wbuf + off[13];
    const float* f_mW2 = wbuf + off[14]; const float* f_mb2 = wbuf + off[15];
    const float* f_oW1 = wbuf + off[16]; const float* f_ob1 = wbuf + off[17];
    const float* f_oW2 = wbuf + off[18]; const float* f_ob2 = wbuf + off[19];

    embed_kernel<<<NTOK, 256, 0, stream>>>(d_in[0], flag, f_inpW1, f_inpb1,
                                           f_inpW2, f_inpb2, pdsy, pdsx, bufd);

    for (int l = 0; l < 4; ++l) {
        int sh = l & 1;
        const float* Wql = f_Wq + l * 4096;  const float* bql = f_bq + l * 64;
        const float* Wkl = f_Wk + l * 4096;  const float* bkl = f_bk + l * 64;
        const float* Wvl = f_Wv + l * 4096;  const float* bvl = f_bv + l * 64;
        const float* Wol = f_Wo + l * 4096;  const float* bol = f_bo + l * 64;
        const float* W1l = f_mW1 + l * 4096; const float* b1l = f_mb1 + l * 64;
        const float* W2l = f_mW2 + l * 4096; const float* b2l = f_mb2 + l * 64;

        norm_xhat<<<NTOK, 256, 0, stream>>>(bufd, xhat);
        scores_fused<<<dim3(128, 4), 256, 0, stream>>>(xhat, Wql, bql, Wkl, bkl, sh, A);
        for (int hb = 0; hb < 4; hb += 2) {
            av_fused<<<dim3(128, 2), 256, 0, stream>>>(xhat, Wvl, bvl, A, sh, hb, oslab);
            if (sh) wo_accum<true ><<<NTOK, 256, 0, stream>>>(oslab, hb, Wol, bol, bufd);
            else    wo_accum<false><<<NTOK, 256, 0, stream>>>(oslab, hb, Wol, bol, bufd);
        }
        norm_xhat<<<NTOK, 256, 0, stream>>>(bufd, xhat);
        mlp_fused<<<NTOK, 256, 0, stream>>>(bufd, xhat, W1l, b1l, W2l, b2l);
    }

    out_mlp<<<NTOK, 256, 0, stream>>>(bufd, f_oW1, f_ob1, f_oW2, f_ob2, d_out, flag);
}

// Round 5
// 9096.095 us; speedup vs baseline: 2.5107x; 2.5107x over previous
//
#include <hip/hip_runtime.h>
#include <math.h>

typedef unsigned short u16;
typedef unsigned int   u32;
typedef __attribute__((ext_vector_type(8))) short bf16x8;
typedef __attribute__((ext_vector_type(4))) float f32x4;

// ---------------- problem constants ----------------------------------------
// B=8, H=W=256, E=64, HID=128, SUB=16, WS=4, NH=4, dh=16, L=4
// tokens: 2048; residual d [n][256 px][64 ch] fp32; xhat same in bf16
// q/k/v/o head slabs: [slab h][tok][px][16ch] bf16, 4096 elems per (h,tok)
#define NTOK  2048
#define TOKSZ 16384ull
#define DSZ   (2048ull*16384ull)
#define HSL   (2048ull*4096ull)

__device__ __forceinline__ float bf2f(u16 b) { return __uint_as_float(((u32)b) << 16); }
__device__ __forceinline__ u16 f2bf(float f) {
    u32 u = __float_as_uint(f);
    u += 0x7FFFu + ((u >> 16) & 1u);
    return (u16)(u >> 16);
}
__device__ __forceinline__ float gelu_f(float x) {
    return 0.5f * x * (1.0f + erff(x * 0.70710678118654752440f));
}
__device__ __forceinline__ int shift_tok(int n) {
    int w = n >> 4, s = n & 15;
    int b = w >> 4, wy = (w >> 2) & 3, wx = w & 3;
    int ty = s >> 2, tx = s & 3;
    int gy = ((wy << 2) + ty + 2) & 15;
    int gx = ((wx << 2) + tx + 2) & 15;
    int w2 = (b << 4) + ((gy >> 2) << 2) + (gx >> 2);
    int s2 = ((gy & 3) << 2) + (gx & 3);
    return (w2 << 4) + s2;
}

#define UNPACK8(xb, x0,x1,x2,x3,x4,x5,x6,x7)                      \
    float x0 = __uint_as_float(xb.x << 16);                       \
    float x1 = __uint_as_float(xb.x & 0xFFFF0000u);               \
    float x2 = __uint_as_float(xb.y << 16);                       \
    float x3 = __uint_as_float(xb.y & 0xFFFF0000u);               \
    float x4 = __uint_as_float(xb.z << 16);                       \
    float x5 = __uint_as_float(xb.z & 0xFFFF0000u);               \
    float x6 = __uint_as_float(xb.w << 16);                       \
    float x7 = __uint_as_float(xb.w & 0xFFFF0000u);

union U8 { uint4 u; bf16x8 b; };

// ---------------- dtype detection (proven round 4) -------------------------
__global__ void detect_kernel(const u16* __restrict__ w1, int* __restrict__ flag) {
    int t = threadIdx.x, bad = 0;
    for (int i = t; i < 640; i += 64) {
        float ax = fabsf(bf2f(w1[i]));
        if (!(ax < 1e3f)) bad = 1;
    }
    unsigned long long m = __ballot(bad);
    if (t == 0) *flag = (m != 0ull) ? 1 : 0;
}

#define NWT 20
struct WArgs { const void* src[NWT]; int off[NWT + 1]; };

__global__ __launch_bounds__(256)
void cvt_weights(WArgs a, const int* __restrict__ flag, float* __restrict__ wbuf) {
    int t = blockIdx.x * 256 + threadIdx.x;
    if (t >= a.off[NWT]) return;
    int s = 0;
    while (a.off[s + 1] <= t) ++s;
    int idx = t - a.off[s];
    wbuf[t] = (*flag) ? ((const float*)a.src[s])[idx]
                      : bf2f(((const u16*)a.src[s])[idx]);
}

// ---------------- input embed (two 32-channel halves, no spill) ------------
__global__ __launch_bounds__(256, 2)
void embed_kernel(const void* __restrict__ vin, const int* __restrict__ flag,
                  const float* __restrict__ W1, const float* __restrict__ b1,
                  const float* __restrict__ W2, const float* __restrict__ b2,
                  const int* __restrict__ pdsy, const int* __restrict__ pdsx,
                  float* __restrict__ d) {
    int n = blockIdx.x, p = threadIdx.x;
    int w = n >> 4, s = n & 15;
    int b = w >> 4, wy = (w >> 2) & 3, wx = w & 3;
    int ty = s >> 2, tx = s & 3;
    int y = ((wy << 2) + ty) * 16 + (p >> 4);
    int x = ((wx << 2) + tx) * 16 + (p & 15);
    float sy = (float)pdsy[0] * (1.0f / 256.0f);
    float sx = (float)pdsx[0] * (1.0f / 256.0f);
    int fl = *flag;

    float in[5];
    in[0] = ((float)y + 0.5f) * sy;
    in[1] = ((float)x + 0.5f) * sx;
    size_t pix = (size_t)b * 3 * 65536 + (size_t)y * 256 + (size_t)x;
    #pragma unroll
    for (int c = 0; c < 3; ++c)
        in[2 + c] = fl ? ((const float*)vin)[pix + (size_t)c * 65536]
                       : bf2f(((const u16*)vin)[pix + (size_t)c * 65536]);

    float* dp = d + (size_t)n * TOKSZ + (size_t)p * 64;
    for (int half = 0; half < 2; ++half) {
        float acc[32];
        #pragma unroll
        for (int e = 0; e < 32; ++e) acc[e] = b2[half * 32 + e];
        for (int hid = 0; hid < 128; ++hid) {
            float h = b1[hid];
            #pragma unroll
            for (int c = 0; c < 5; ++c) h = fmaf(W1[hid * 5 + c], in[c], h);
            float g = gelu_f(h);
            #pragma unroll
            for (int e = 0; e < 32; ++e)
                acc[e] = fmaf(W2[(half * 32 + e) * 128 + hid], g, acc[e]);
        }
        #pragma unroll
        for (int e = 0; e < 32; ++e) dp[half * 32 + e] = acc[e];
    }
}

// ---------------- InstanceNorm -> bf16 xhat (proven round 4) ---------------
__global__ __launch_bounds__(256)
void norm_xhat(const float* __restrict__ d, u16* __restrict__ xhat) {
    int n = blockIdx.x, t = threadIdx.x;
    int c = t & 63, qdr = t >> 6;
    const float* dp0 = d + (size_t)n * TOKSZ + qdr * 4096 + c;
    float s = 0.f, q = 0.f;
    #pragma unroll 8
    for (int pp = 0; pp < 64; ++pp) {
        float x = dp0[pp * 64];
        s += x; q = fmaf(x, x, q);
    }
    __shared__ float red[2][4][64];
    __shared__ float mu[64], rs[64];
    red[0][qdr][c] = s; red[1][qdr][c] = q;
    __syncthreads();
    if (t < 64) {
        float ss = red[0][0][t] + red[0][1][t] + red[0][2][t] + red[0][3][t];
        float qq = red[1][0][t] + red[1][1][t] + red[1][2][t] + red[1][3][t];
        float m = ss * (1.0f / 256.0f);
        float var = qq * (1.0f / 256.0f) - m * m;
        mu[t] = m; rs[t] = rsqrtf(var + 1e-5f);
    }
    __syncthreads();
    const float4* dp4 = (const float4*)(d + (size_t)n * TOKSZ + (size_t)t * 64);
    u32* xo = (u32*)(xhat + (size_t)n * TOKSZ + (size_t)t * 64);
    #pragma unroll
    for (int c2 = 0; c2 < 16; ++c2) {
        float4 x = dp4[c2];
        int cb = c2 * 4;
        u32 w0 = (u32)f2bf((x.x - mu[cb])     * rs[cb])
               | ((u32)f2bf((x.y - mu[cb + 1]) * rs[cb + 1]) << 16);
        u32 w1 = (u32)f2bf((x.z - mu[cb + 2]) * rs[cb + 2])
               | ((u32)f2bf((x.w - mu[cb + 3]) * rs[cb + 3]) << 16);
        xo[c2 * 2] = w0; xo[c2 * 2 + 1] = w1;
    }
}

// ---------------- q,k,v projection (xhat read once, head-major out) --------
__global__ __launch_bounds__(256, 2)
void qkv_proj(const u16* __restrict__ xhat,
              const float* __restrict__ Wq, const float* __restrict__ bq,
              const float* __restrict__ Wk, const float* __restrict__ bk,
              const float* __restrict__ Wv, const float* __restrict__ bv,
              int hbase, int hN,
              u16* __restrict__ q, u16* __restrict__ k, u16* __restrict__ v) {
    int n = blockIdx.x, px = threadIdx.x;
    const uint4* xr = (const uint4*)(xhat + (size_t)n * TOKSZ + (size_t)px * 64);
    const float* Ws[3] = {Wq, Wk, Wv};
    const float* bs[3] = {bq, bk, bv};
    u16* outs[3] = {q, k, v};

    for (int ti = 0; ti < 3; ++ti) {
        const float* W = Ws[ti];
        const float* bb = bs[ti];
        for (int hh = 0; hh < hN; ++hh) {
            int h = hbase + hh;
            float acc[16];
            #pragma unroll
            for (int e2 = 0; e2 < 16; ++e2) acc[e2] = bb[h * 16 + e2];
            for (int c8 = 0; c8 < 8; ++c8) {
                uint4 xb = xr[c8];
                UNPACK8(xb, x0,x1,x2,x3,x4,x5,x6,x7)
                #pragma unroll
                for (int e2 = 0; e2 < 16; ++e2) {
                    const float* wr = W + (h * 16 + e2) * 64 + c8 * 8;
                    acc[e2] = fmaf(wr[0], x0, acc[e2]);
                    acc[e2] = fmaf(wr[1], x1, acc[e2]);
                    acc[e2] = fmaf(wr[2], x2, acc[e2]);
                    acc[e2] = fmaf(wr[3], x3, acc[e2]);
                    acc[e2] = fmaf(wr[4], x4, acc[e2]);
                    acc[e2] = fmaf(wr[5], x5, acc[e2]);
                    acc[e2] = fmaf(wr[6], x6, acc[e2]);
                    acc[e2] = fmaf(wr[7], x7, acc[e2]);
                }
            }
            uint4 o0, o1;
            o0.x = (u32)f2bf(acc[0])  | ((u32)f2bf(acc[1])  << 16);
            o0.y = (u32)f2bf(acc[2])  | ((u32)f2bf(acc[3])  << 16);
            o0.z = (u32)f2bf(acc[4])  | ((u32)f2bf(acc[5])  << 16);
            o0.w = (u32)f2bf(acc[6])  | ((u32)f2bf(acc[7])  << 16);
            o1.x = (u32)f2bf(acc[8])  | ((u32)f2bf(acc[9])  << 16);
            o1.y = (u32)f2bf(acc[10]) | ((u32)f2bf(acc[11]) << 16);
            o1.z = (u32)f2bf(acc[12]) | ((u32)f2bf(acc[13]) << 16);
            o1.w = (u32)f2bf(acc[14]) | ((u32)f2bf(acc[15]) << 16);
            uint4* op = (uint4*)(outs[ti] + ((size_t)hh * 2048 + n) * 4096 + (size_t)px * 16);
            op[0] = o0; op[1] = o1;
        }
    }
}

// ---------------- scores via MFMA 16x16x32 + softmax -----------------------
// block = (window, slab-head); 4 waves split K=4096; any consistent k-perm in
// the A/B frags cancels in the dot; C/D mapping is the m89-verified one.
__global__ __launch_bounds__(256, 4)
void scores_mfma(const u16* __restrict__ q, const u16* __restrict__ k,
                 int shifted, int hbase, float* __restrict__ A) {
    int w = blockIdx.x, hs = blockIdx.y, t = threadIdx.x;
    int wv = t >> 6, l = t & 63;
    int m = l & 15, qd = l >> 4;
    int n0 = w * 16 + m;
    int ni = shifted ? shift_tok(n0) : n0;
    const u16* qrow = q + ((size_t)hs * 2048 + ni) * 4096;
    const u16* krow = k + ((size_t)hs * 2048 + ni) * 4096;
    f32x4 acc = {0.f, 0.f, 0.f, 0.f};
    int kb = wv * 1024 + qd * 8;
    for (int s = 0; s < 32; ++s) {
        U8 qa, kv;
        qa.u = *(const uint4*)(qrow + kb + s * 32);
        kv.u = *(const uint4*)(krow + kb + s * 32);
        acc = __builtin_amdgcn_mfma_f32_16x16x32_bf16(qa.b, kv.b, acc, 0, 0, 0);
    }
    __shared__ float pc[4][256];
    #pragma unroll
    for (int r = 0; r < 4; ++r) pc[wv][l * 4 + r] = acc[r];
    __syncthreads();
    if (wv == 0) {
        float* arow = A + ((size_t)(w * 4 + hbase + hs) * 16) * 16;
        #pragma unroll
        for (int r = 0; r < 4; ++r) {
            float sc = (pc[0][l*4+r] + pc[1][l*4+r] + pc[2][l*4+r] + pc[3][l*4+r])
                     * (1.0f / 1024.0f);
            float mx = sc;
            #pragma unroll
            for (int off = 1; off < 16; off <<= 1) mx = fmaxf(mx, __shfl_xor(mx, off, 16));
            float e = expf(sc - mx);
            float ssum = e;
            #pragma unroll
            for (int off = 1; off < 16; off <<= 1) ssum += __shfl_xor(ssum, off, 16);
            arow[(qd * 4 + r) * 16 + m] = e / ssum;   // row i = qd*4+r, col j = m
        }
    }
}

// ---------------- o = A @ v (A via wave-uniform scalar loads) --------------
__global__ __launch_bounds__(256, 4)
void av_kernel(const u16* __restrict__ v, const float* __restrict__ A,
               int shifted, int hbase, u16* __restrict__ o) {
    int w = blockIdx.x, hs = blockIdx.y, t = threadIdx.x;
    __shared__ int nis[16];
    if (t < 16) { int n = w * 16 + t; nis[t] = shifted ? shift_tok(n) : n; }
    __syncthreads();
    const float* Ab = A + (size_t)(w * 4 + hbase + hs) * 256;
    const u16* vsl = v + (size_t)hs * HSL;
    u16* osl = o + (size_t)hs * HSL;

    for (int cc = 0; cc < 8; ++cc) {
        int colb = cc * 512 + t * 2;
        float v0[16], v1[16];
        #pragma unroll
        for (int j = 0; j < 16; ++j) {
            u32 pv = *(const u32*)(vsl + (size_t)nis[j] * 4096 + colb);
            v0[j] = __uint_as_float(pv << 16);
            v1[j] = __uint_as_float(pv & 0xFFFF0000u);
        }
        #pragma unroll
        for (int i = 0; i < 16; ++i) {
            float a0 = 0.f, a1 = 0.f;
            #pragma unroll
            for (int j = 0; j < 16; ++j) {
                float aw = Ab[i * 16 + j];
                a0 = fmaf(aw, v0[j], a0);
                a1 = fmaf(aw, v1[j], a1);
            }
            *(u32*)(osl + (size_t)(w * 16 + i) * 4096 + colb)
                = (u32)f2bf(a0) | ((u32)f2bf(a1) << 16);
        }
    }
}

// ---------------- Wo projection + residual accumulate ----------------------
__global__ __launch_bounds__(256, 2)
void wo_accum(const u16* __restrict__ o, int hbase, int hN,
              const float* __restrict__ Wo, const float* __restrict__ bo,
              int shifted, float* __restrict__ dres) {
    int n = blockIdx.x, p = threadIdx.x;
    int no = shifted ? shift_tok(n) : n;
    float acc[64];
    if (hbase == 0) {
        #pragma unroll
        for (int e = 0; e < 64; ++e) acc[e] = bo[e];
    } else {
        #pragma unroll
        for (int e = 0; e < 64; ++e) acc[e] = 0.f;
    }
    for (int hh = 0; hh < hN; ++hh) {
        const uint4* op4 = (const uint4*)(o + ((size_t)hh * 2048 + n) * 4096 + (size_t)p * 16);
        float xv[16];
        {
            uint4 xb = op4[0];
            UNPACK8(xb, x0,x1,x2,x3,x4,x5,x6,x7)
            xv[0]=x0; xv[1]=x1; xv[2]=x2; xv[3]=x3; xv[4]=x4; xv[5]=x5; xv[6]=x6; xv[7]=x7;
        }
        {
            uint4 xb = op4[1];
            UNPACK8(xb, x0,x1,x2,x3,x4,x5,x6,x7)
            xv[8]=x0; xv[9]=x1; xv[10]=x2; xv[11]=x3; xv[12]=x4; xv[13]=x5; xv[14]=x6; xv[15]=x7;
        }
        int hc = (hbase + hh) * 16;
        #pragma unroll
        for (int c2 = 0; c2 < 16; ++c2) {
            #pragma unroll
            for (int e = 0; e < 64; ++e)
                acc[e] = fmaf(Wo[e * 64 + hc + c2], xv[c2], acc[e]);
        }
    }
    float* dp = dres + (size_t)no * TOKSZ + (size_t)p * 64;
    #pragma unroll
    for (int e = 0; e < 64; ++e) dp[e] += acc[e];
}

// ---------------- fused MLP: d += W2 gelu(W1 xhat + b1) + b2 ---------------
__global__ __launch_bounds__(256, 2)
void mlp_fused(float* __restrict__ dres, const u16* __restrict__ xhat,
               const float* __restrict__ W1, const float* __restrict__ b1,
               const float* __restrict__ W2, const float* __restrict__ b2) {
    int n = blockIdx.x, p = threadIdx.x;
    float xh[64];
    const uint4* xr = (const uint4*)(xhat + (size_t)n * TOKSZ + (size_t)p * 64);
    #pragma unroll
    for (int c8 = 0; c8 < 8; ++c8) {
        uint4 xb = xr[c8];
        UNPACK8(xb, x0,x1,x2,x3,x4,x5,x6,x7)
        xh[c8*8+0]=x0; xh[c8*8+1]=x1; xh[c8*8+2]=x2; xh[c8*8+3]=x3;
        xh[c8*8+4]=x4; xh[c8*8+5]=x5; xh[c8*8+6]=x6; xh[c8*8+7]=x7;
    }
    float hb[64];
    for (int c2 = 0; c2 < 64; ++c2) {
        float a = b1[c2];
        #pragma unroll
        for (int c = 0; c < 64; ++c) a = fmaf(W1[c2 * 64 + c], xh[c], a);
        hb[c2] = gelu_f(a);
    }
    float* dp = dres + (size_t)n * TOKSZ + (size_t)p * 64;
    for (int e = 0; e < 64; ++e) {
        float a = b2[e];
        #pragma unroll
        for (int c2 = 0; c2 < 64; ++c2) a = fmaf(W2[e * 64 + c2], hb[c2], a);
        dp[e] += a;
    }
}

// ---------------- output MLP: 64 -> 128(gelu) -> 1 -------------------------
__global__ __launch_bounds__(256, 2)
void out_mlp(const float* __restrict__ d,
             const float* __restrict__ W1, const float* __restrict__ b1,
             const float* __restrict__ W2, const float* __restrict__ b2,
             void* __restrict__ out, const int* __restrict__ flag) {
    int n = blockIdx.x, p = threadIdx.x;
    const float* dp = d + (size_t)n * TOKSZ + (size_t)p * 64;
    float xr[64];
    #pragma unroll
    for (int e = 0; e < 64; ++e) xr[e] = dp[e];
    float acc = b2[0];
    for (int hid = 0; hid < 128; ++hid) {
        float h = b1[hid];
        #pragma unroll
        for (int e = 0; e < 64; ++e) h = fmaf(W1[hid * 64 + e], xr[e], h);
        acc = fmaf(W2[hid], gelu_f(h), acc);
    }
    int w = n >> 4, s = n & 15;
    int b = w >> 4, wy = (w >> 2) & 3, wx = w & 3;
    int ty = s >> 2, tx = s & 3;
    int y = ((wy << 2) + ty) * 16 + (p >> 4);
    int x = ((wx << 2) + tx) * 16 + (p & 15);
    size_t oi = (size_t)b * 65536 + (size_t)y * 256 + (size_t)x;
    if (*flag) ((float*)out)[oi] = acc;
    else       ((u16*)out)[oi] = f2bf(acc);
}

// ---------------- host launch ----------------------------------------------
extern "C" void kernel_launch(void* const* d_in, const int* in_sizes, int n_in,
                              void* d_out, int out_size, void* d_ws, size_t ws_size,
                              hipStream_t stream) {
    (void)n_in; (void)out_size;
    const int* pdsy = (const int*)d_in[21];
    const int* pdsx = (const int*)d_in[22];

    // fixed layout: bufd f32 128MB | xhat bf16 64MB | A 512KB | wbuf 512KB | flag
    char* wsb = (char*)d_ws;
    float* bufd = (float*)wsb;
    u16*   xhat = (u16*)(wsb + 134217728ull);
    float* A    = (float*)(wsb + 201326592ull);
    float* wbuf = (float*)(wsb + 201850880ull);
    int*   flag = (int*)(wsb + 202375168ull);
    size_t slabOff = 202375680ull;

    // adaptive head grouping by available workspace (deterministic per session)
    int hN; size_t slabB;
    if      (ws_size >= slabOff + 3ull * 67108864ull) { hN = 4; slabB = 67108864ull; }
    else if (ws_size >= slabOff + 3ull * 33554432ull) { hN = 2; slabB = 33554432ull; }
    else                                              { hN = 1; slabB = 16777216ull; }
    u16* qb = (u16*)(wsb + slabOff);
    u16* kb = (u16*)(wsb + slabOff + slabB);
    u16* vb = (u16*)(wsb + slabOff + 2 * slabB);
    u16* ob = qb;   // q dead after scores; reuse as o

    WArgs wa;
    int off[NWT + 1]; off[0] = 0;
    for (int i = 0; i < NWT; ++i) {
        wa.src[i] = d_in[i + 1];
        off[i + 1] = off[i] + in_sizes[i + 1];
        wa.off[i] = off[i];
    }
    wa.off[NWT] = off[NWT];

    detect_kernel<<<1, 64, 0, stream>>>((const u16*)d_in[1], flag);
    cvt_weights<<<(off[NWT] + 255) / 256, 256, 0, stream>>>(wa, flag, wbuf);

    const float* f_inpW1 = wbuf + off[0];
    const float* f_inpb1 = wbuf + off[1];
    const float* f_inpW2 = wbuf + off[2];
    const float* f_inpb2 = wbuf + off[3];
    const float* f_Wq = wbuf + off[4];   const float* f_bq = wbuf + off[5];
    const float* f_Wk = wbuf + off[6];   const float* f_bk = wbuf + off[7];
    const float* f_Wv = wbuf + off[8];   const float* f_bv = wbuf + off[9];
    const float* f_Wo = wbuf + off[10];  const float* f_bo = wbuf + off[11];
    const float* f_mW1 = wbuf + off[12]; const float* f_mb1 = wbuf + off[13];
    const float* f_mW2 = wbuf + off[14]; const float* f_mb2 = wbuf + off[15];
    const float* f_oW1 = wbuf + off[16]; const float* f_ob1 = wbuf + off[17];
    const float* f_oW2 = wbuf + off[18]; const float* f_ob2 = wbuf + off[19];

    embed_kernel<<<NTOK, 256, 0, stream>>>(d_in[0], flag, f_inpW1, f_inpb1,
                                           f_inpW2, f_inpb2, pdsy, pdsx, bufd);

    for (int l = 0; l < 4; ++l) {
        int sh = l & 1;
        const float* Wql = f_Wq + l * 4096;  const float* bql = f_bq + l * 64;
        const float* Wkl = f_Wk + l * 4096;  const float* bkl = f_bk + l * 64;
        const float* Wvl = f_Wv + l * 4096;  const float* bvl = f_bv + l * 64;
        const float* Wol = f_Wo + l * 4096;  const float* bol = f_bo + l * 64;
        const float* W1l = f_mW1 + l * 4096; const float* b1l = f_mb1 + l * 64;
        const float* W2l = f_mW2 + l * 4096; const float* b2l = f_mb2 + l * 64;

        norm_xhat<<<NTOK, 256, 0, stream>>>(bufd, xhat);
        for (int hb2 = 0; hb2 < 4; hb2 += hN) {
            qkv_proj<<<NTOK, 256, 0, stream>>>(xhat, Wql, bql, Wkl, bkl, Wvl, bvl,
                                               hb2, hN, qb, kb, vb);
            scores_mfma<<<dim3(128, hN), 256, 0, stream>>>(qb, kb, sh, hb2, A);
            av_kernel<<<dim3(128, hN), 256, 0, stream>>>(vb, A, sh, hb2, ob);
            wo_accum<<<NTOK, 256, 0, stream>>>(ob, hb2, hN, Wol, bol, sh, bufd);
        }
        norm_xhat<<<NTOK, 256, 0, stream>>>(bufd, xhat);
        mlp_fused<<<NTOK, 256, 0, stream>>>(bufd, xhat, W1l, b1l, W2l, b2l);
    }

    out_mlp<<<NTOK, 256, 0, stream>>>(bufd, f_oW1, f_ob1, f_oW2, f_ob2, d_out, flag);
}

// Round 6
// 6926.954 us; speedup vs baseline: 3.2970x; 1.3131x over previous
//
#include <hip/hip_runtime.h>
#include <math.h>

typedef unsigned short u16;
typedef unsigned int   u32;
typedef __attribute__((ext_vector_type(8))) short bf16x8;
typedef __attribute__((ext_vector_type(4))) float f32x4;

// ---------------- problem constants ----------------------------------------
// B=8, H=W=256, E=64, HID=128, SUB=16, WS=4, NH=4, dh=16, L=4
// tokens: 2048; residual d [n][256 px][64 ch] fp32; xhat same in bf16
// q/k/v/o head slabs: [h][tok][px][16ch] bf16
#define NTOK  2048
#define TOKSZ 16384ull
#define DSZ   (2048ull*16384ull)
#define HSL   (2048ull*4096ull)

__device__ __forceinline__ float bf2f(u16 b) { return __uint_as_float(((u32)b) << 16); }
__device__ __forceinline__ u16 f2bf(float f) {
    u32 u = __float_as_uint(f);
    u += 0x7FFFu + ((u >> 16) & 1u);
    return (u16)(u >> 16);
}
__device__ __forceinline__ float gelu_f(float x) {
    return 0.5f * x * (1.0f + erff(x * 0.70710678118654752440f));
}
__device__ __forceinline__ int shift_tok(int n) {
    int w = n >> 4, s = n & 15;
    int b = w >> 4, wy = (w >> 2) & 3, wx = w & 3;
    int ty = s >> 2, tx = s & 3;
    int gy = ((wy << 2) + ty + 2) & 15;
    int gx = ((wx << 2) + tx + 2) & 15;
    int w2 = (b << 4) + ((gy >> 2) << 2) + (gx >> 2);
    int s2 = ((gy & 3) << 2) + (gx & 3);
    return (w2 << 4) + s2;
}

#define UNPACK8(xb, x0,x1,x2,x3,x4,x5,x6,x7)                      \
    float x0 = __uint_as_float(xb.x << 16);                       \
    float x1 = __uint_as_float(xb.x & 0xFFFF0000u);               \
    float x2 = __uint_as_float(xb.y << 16);                       \
    float x3 = __uint_as_float(xb.y & 0xFFFF0000u);               \
    float x4 = __uint_as_float(xb.z << 16);                       \
    float x5 = __uint_as_float(xb.z & 0xFFFF0000u);               \
    float x6 = __uint_as_float(xb.w << 16);                       \
    float x7 = __uint_as_float(xb.w & 0xFFFF0000u);

union U8 { uint4 u; bf16x8 b; };

// ---------------- dtype detection (proven) ---------------------------------
__global__ void detect_kernel(const u16* __restrict__ w1, int* __restrict__ flag) {
    int t = threadIdx.x, bad = 0;
    for (int i = t; i < 640; i += 64) {
        float ax = fabsf(bf2f(w1[i]));
        if (!(ax < 1e3f)) bad = 1;
    }
    unsigned long long m = __ballot(bad);
    if (t == 0) *flag = (m != 0ull) ? 1 : 0;
}

#define NWT 20
struct WArgs { const void* src[NWT]; int off[NWT + 1]; };

__global__ __launch_bounds__(256)
void cvt_weights(WArgs a, const int* __restrict__ flag,
                 float* __restrict__ wbuf, u16* __restrict__ wbuf16) {
    int t = blockIdx.x * 256 + threadIdx.x;
    if (t >= a.off[NWT]) return;
    int s = 0;
    while (a.off[s + 1] <= t) ++s;
    int idx = t - a.off[s];
    if (*flag) {
        float v = ((const float*)a.src[s])[idx];
        wbuf[t] = v; wbuf16[t] = f2bf(v);
    } else {
        u16 r = ((const u16*)a.src[s])[idx];
        wbuf[t] = bf2f(r); wbuf16[t] = r;
    }
}

// ---------------- input embed (unchanged) ----------------------------------
__global__ __launch_bounds__(256, 2)
void embed_kernel(const void* __restrict__ vin, const int* __restrict__ flag,
                  const float* __restrict__ W1, const float* __restrict__ b1,
                  const float* __restrict__ W2, const float* __restrict__ b2,
                  const int* __restrict__ pdsy, const int* __restrict__ pdsx,
                  float* __restrict__ d) {
    int n = blockIdx.x, p = threadIdx.x;
    int w = n >> 4, s = n & 15;
    int b = w >> 4, wy = (w >> 2) & 3, wx = w & 3;
    int ty = s >> 2, tx = s & 3;
    int y = ((wy << 2) + ty) * 16 + (p >> 4);
    int x = ((wx << 2) + tx) * 16 + (p & 15);
    float sy = (float)pdsy[0] * (1.0f / 256.0f);
    float sx = (float)pdsx[0] * (1.0f / 256.0f);
    int fl = *flag;

    float in[5];
    in[0] = ((float)y + 0.5f) * sy;
    in[1] = ((float)x + 0.5f) * sx;
    size_t pix = (size_t)b * 3 * 65536 + (size_t)y * 256 + (size_t)x;
    #pragma unroll
    for (int c = 0; c < 3; ++c)
        in[2 + c] = fl ? ((const float*)vin)[pix + (size_t)c * 65536]
                       : bf2f(((const u16*)vin)[pix + (size_t)c * 65536]);

    float* dp = d + (size_t)n * TOKSZ + (size_t)p * 64;
    for (int half = 0; half < 2; ++half) {
        float acc[32];
        #pragma unroll
        for (int e = 0; e < 32; ++e) acc[e] = b2[half * 32 + e];
        for (int hid = 0; hid < 128; ++hid) {
            float h = b1[hid];
            #pragma unroll
            for (int c = 0; c < 5; ++c) h = fmaf(W1[hid * 5 + c], in[c], h);
            float g = gelu_f(h);
            #pragma unroll
            for (int e = 0; e < 32; ++e)
                acc[e] = fmaf(W2[(half * 32 + e) * 128 + hid], g, acc[e]);
        }
        #pragma unroll
        for (int e = 0; e < 32; ++e) dp[half * 32 + e] = acc[e];
    }
}

// ---------------- InstanceNorm -> bf16 xhat (coalesced pass 2) --------------
__global__ __launch_bounds__(256)
void norm_xhat(const float* __restrict__ d, u16* __restrict__ xhat) {
    int n = blockIdx.x, t = threadIdx.x;
    int c = t & 63, qdr = t >> 6;
    const float* dp0 = d + (size_t)n * TOKSZ + qdr * 4096 + c;
    float s = 0.f, q = 0.f;
    #pragma unroll 8
    for (int pp = 0; pp < 64; ++pp) {
        float x = dp0[pp * 64];
        s += x; q = fmaf(x, x, q);
    }
    __shared__ float red[2][4][64];
    __shared__ float mu[64], rs[64];
    red[0][qdr][c] = s; red[1][qdr][c] = q;
    __syncthreads();
    if (t < 64) {
        float ss = red[0][0][t] + red[0][1][t] + red[0][2][t] + red[0][3][t];
        float qq = red[1][0][t] + red[1][1][t] + red[1][2][t] + red[1][3][t];
        float m = ss * (1.0f / 256.0f);
        float var = qq * (1.0f / 256.0f) - m * m;
        mu[t] = m; rs[t] = rsqrtf(var + 1e-5f);
    }
    __syncthreads();
    // channel of float idx 4t + 1024r is (4t)&63 for all r -> loop-constant mu/rs
    int cb = (4 * t) & 63;
    float m0 = mu[cb], m1 = mu[cb + 1], m2 = mu[cb + 2], m3 = mu[cb + 3];
    float r0 = rs[cb], r1 = rs[cb + 1], r2 = rs[cb + 2], r3 = rs[cb + 3];
    const float4* gin = (const float4*)(d + (size_t)n * TOKSZ);
    uint2* gout = (uint2*)(xhat + (size_t)n * TOKSZ);
    #pragma unroll
    for (int r = 0; r < 16; ++r) {
        float4 x = gin[t + r * 256];
        uint2 o;
        o.x = (u32)f2bf((x.x - m0) * r0) | ((u32)f2bf((x.y - m1) * r1) << 16);
        o.y = (u32)f2bf((x.z - m2) * r2) | ((u32)f2bf((x.w - m3) * r3) << 16);
        gout[t + r * 256] = o;
    }
}

// ---------------- MFMA q,k,v projection (all 4 heads) ----------------------
__global__ __launch_bounds__(256, 3)
void qkv_mfma(const u16* __restrict__ xhat,
              const u16* __restrict__ Wq16, const float* __restrict__ bq,
              const u16* __restrict__ Wk16, const float* __restrict__ bk,
              const u16* __restrict__ Wv16, const float* __restrict__ bv,
              u16* __restrict__ q, u16* __restrict__ k, u16* __restrict__ v) {
    int n = blockIdx.x, t = threadIdx.x;
    int wv = t >> 6, l = t & 63, m = l & 15, qd = l >> 4;
    __shared__ __align__(16) u16 xs[256 * 72];
    __shared__ __align__(16) u16 wl[64 * 64];
    const uint4* gx = (const uint4*)(xhat + (size_t)n * TOKSZ);
    #pragma unroll
    for (int r = 0; r < 8; ++r) {
        int u = t + r * 256;
        int px = u >> 3, c8 = u & 7;
        *(uint4*)&xs[px * 72 + c8 * 8] = gx[u];
    }
    const u16* Ws[3] = {Wq16, Wk16, Wv16};
    const float* bs[3] = {bq, bk, bv};
    u16* outs[3] = {q, k, v};
    int px0 = wv * 64;
    __syncthreads();

    for (int ti = 0; ti < 3; ++ti) {
        const uint4* gw = (const uint4*)Ws[ti];
        #pragma unroll
        for (int r = 0; r < 2; ++r) {
            int u = t + r * 256;
            *(uint4*)&wl[u * 8] = gw[u];
        }
        __syncthreads();
        f32x4 acc[4][4];
        #pragma unroll
        for (int nt = 0; nt < 4; ++nt) {
            float b = bs[ti][nt * 16 + m];
            #pragma unroll
            for (int mt = 0; mt < 4; ++mt) acc[mt][nt] = {b, b, b, b};
        }
        #pragma unroll
        for (int ks = 0; ks < 2; ++ks) {
            U8 af[4], bf[4];
            #pragma unroll
            for (int mt = 0; mt < 4; ++mt)
                af[mt].u = *(const uint4*)&xs[(px0 + mt * 16 + m) * 72 + ks * 32 + qd * 8];
            #pragma unroll
            for (int nt = 0; nt < 4; ++nt)
                bf[nt].u = *(const uint4*)&wl[(nt * 16 + m) * 64 + ks * 32 + qd * 8];
            #pragma unroll
            for (int mt = 0; mt < 4; ++mt) {
                #pragma unroll
                for (int nt = 0; nt < 4; ++nt)
                    acc[mt][nt] = __builtin_amdgcn_mfma_f32_16x16x32_bf16(
                        af[mt].b, bf[nt].b, acc[mt][nt], 0, 0, 0);
            }
        }
        // direct store: head h = nt, c2 = m
        #pragma unroll
        for (int nt = 0; nt < 4; ++nt) {
            u16* hb = outs[ti] + ((size_t)nt * 2048 + n) * 4096 + m;
            #pragma unroll
            for (int mt = 0; mt < 4; ++mt) {
                #pragma unroll
                for (int r = 0; r < 4; ++r) {
                    int px = px0 + mt * 16 + qd * 4 + r;
                    hb[px * 16] = f2bf(acc[mt][nt][r]);
                }
            }
        }
        __syncthreads();
    }
}

// ---------------- scores via MFMA + softmax (proven round 5) ---------------
__global__ __launch_bounds__(256, 4)
void scores_mfma(const u16* __restrict__ q, const u16* __restrict__ k,
                 int shifted, int hbase, float* __restrict__ A) {
    int w = blockIdx.x, hs = blockIdx.y, t = threadIdx.x;
    int wv = t >> 6, l = t & 63;
    int m = l & 15, qd = l >> 4;
    int n0 = w * 16 + m;
    int ni = shifted ? shift_tok(n0) : n0;
    const u16* qrow = q + ((size_t)hs * 2048 + ni) * 4096;
    const u16* krow = k + ((size_t)hs * 2048 + ni) * 4096;
    f32x4 acc = {0.f, 0.f, 0.f, 0.f};
    int kb = wv * 1024 + qd * 8;
    for (int s = 0; s < 32; ++s) {
        U8 qa, kv;
        qa.u = *(const uint4*)(qrow + kb + s * 32);
        kv.u = *(const uint4*)(krow + kb + s * 32);
        acc = __builtin_amdgcn_mfma_f32_16x16x32_bf16(qa.b, kv.b, acc, 0, 0, 0);
    }
    __shared__ float pc[4][256];
    #pragma unroll
    for (int r = 0; r < 4; ++r) pc[wv][l * 4 + r] = acc[r];
    __syncthreads();
    if (wv == 0) {
        float* arow = A + ((size_t)(w * 4 + hbase + hs) * 16) * 16;
        #pragma unroll
        for (int r = 0; r < 4; ++r) {
            float sc = (pc[0][l*4+r] + pc[1][l*4+r] + pc[2][l*4+r] + pc[3][l*4+r])
                     * (1.0f / 1024.0f);
            float mx = sc;
            #pragma unroll
            for (int off = 1; off < 16; off <<= 1) mx = fmaxf(mx, __shfl_xor(mx, off, 16));
            float e = expf(sc - mx);
            float ssum = e;
            #pragma unroll
            for (int off = 1; off < 16; off <<= 1) ssum += __shfl_xor(ssum, off, 16);
            arow[(qd * 4 + r) * 16 + m] = e / ssum;
        }
    }
}

// ---------------- o = A @ v (proven round 5) -------------------------------
__global__ __launch_bounds__(256, 4)
void av_kernel(const u16* __restrict__ v, const float* __restrict__ A,
               int shifted, int hbase, u16* __restrict__ o) {
    int w = blockIdx.x, hs = blockIdx.y, t = threadIdx.x;
    __shared__ int nis[16];
    if (t < 16) { int n = w * 16 + t; nis[t] = shifted ? shift_tok(n) : n; }
    __syncthreads();
    const float* Ab = A + (size_t)(w * 4 + hbase + hs) * 256;
    const u16* vsl = v + (size_t)hs * HSL;
    u16* osl = o + (size_t)hs * HSL;

    for (int cc = 0; cc < 8; ++cc) {
        int colb = cc * 512 + t * 2;
        float v0[16], v1[16];
        #pragma unroll
        for (int j = 0; j < 16; ++j) {
            u32 pv = *(const u32*)(vsl + (size_t)nis[j] * 4096 + colb);
            v0[j] = __uint_as_float(pv << 16);
            v1[j] = __uint_as_float(pv & 0xFFFF0000u);
        }
        #pragma unroll
        for (int i = 0; i < 16; ++i) {
            float a0 = 0.f, a1 = 0.f;
            #pragma unroll
            for (int j = 0; j < 16; ++j) {
                float aw = Ab[i * 16 + j];
                a0 = fmaf(aw, v0[j], a0);
                a1 = fmaf(aw, v1[j], a1);
            }
            *(u32*)(osl + (size_t)(w * 16 + i) * 4096 + colb)
                = (u32)f2bf(a0) | ((u32)f2bf(a1) << 16);
        }
    }
}

// ---------------- MFMA Wo projection + residual (4 heads) ------------------
__global__ __launch_bounds__(256, 3)
void wo_mfma(const u16* __restrict__ o, const u16* __restrict__ Wo16,
             const float* __restrict__ bo, int shifted, float* __restrict__ dres) {
    int n = blockIdx.x, t = threadIdx.x;
    int wv = t >> 6, l = t & 63, m = l & 15, qd = l >> 4;
    int no = shifted ? shift_tok(n) : n;
    __shared__ __align__(16) u16 xs[256 * 72];
    __shared__ __align__(16) u16 wl[64 * 64];
    #pragma unroll
    for (int r = 0; r < 8; ++r) {
        int u = t + r * 256;                 // 2048 uint4 over 4 heads
        int h = u >> 9, w2 = u & 511, px = w2 >> 1, c8 = w2 & 1;
        uint4 val = ((const uint4*)(o + ((size_t)h * 2048 + n) * 4096))[w2];
        *(uint4*)&xs[px * 72 + h * 16 + c8 * 8] = val;
    }
    const uint4* gw = (const uint4*)Wo16;
    #pragma unroll
    for (int r = 0; r < 2; ++r) {
        int u = t + r * 256;
        *(uint4*)&wl[u * 8] = gw[u];
    }
    __syncthreads();
    int px0 = wv * 64;
    f32x4 acc[4][4];
    #pragma unroll
    for (int nt = 0; nt < 4; ++nt) {
        float b = bo[nt * 16 + m];
        #pragma unroll
        for (int mt = 0; mt < 4; ++mt) acc[mt][nt] = {b, b, b, b};
    }
    #pragma unroll
    for (int ks = 0; ks < 2; ++ks) {
        U8 af[4], bf[4];
        #pragma unroll
        for (int mt = 0; mt < 4; ++mt)
            af[mt].u = *(const uint4*)&xs[(px0 + mt * 16 + m) * 72 + ks * 32 + qd * 8];
        #pragma unroll
        for (int nt = 0; nt < 4; ++nt)
            bf[nt].u = *(const uint4*)&wl[(nt * 16 + m) * 64 + ks * 32 + qd * 8];
        #pragma unroll
        for (int mt = 0; mt < 4; ++mt) {
            #pragma unroll
            for (int nt = 0; nt < 4; ++nt)
                acc[mt][nt] = __builtin_amdgcn_mfma_f32_16x16x32_bf16(
                    af[mt].b, bf[nt].b, acc[mt][nt], 0, 0, 0);
        }
    }
    float* dp = dres + (size_t)no * TOKSZ;
    #pragma unroll
    for (int nt = 0; nt < 4; ++nt) {
        int ch = nt * 16 + m;
        #pragma unroll
        for (int mt = 0; mt < 4; ++mt) {
            #pragma unroll
            for (int r = 0; r < 4; ++r) {
                int px = px0 + mt * 16 + qd * 4 + r;
                dp[px * 64 + ch] += acc[mt][nt][r];
            }
        }
    }
}

// ---------------- MFMA fused MLP: d += W2 gelu(W1 xhat + b1) + b2 ----------
__global__ __launch_bounds__(256, 2)
void mlp_mfma(float* __restrict__ dres, const u16* __restrict__ xhat,
              const u16* __restrict__ W116, const float* __restrict__ b1,
              const u16* __restrict__ W216, const float* __restrict__ b2) {
    int n = blockIdx.x, t = threadIdx.x;
    int wv = t >> 6, l = t & 63, m = l & 15, qd = l >> 4;
    __shared__ __align__(16) u16 xs[256 * 72];
    __shared__ __align__(16) u16 hs[256 * 72];
    __shared__ __align__(16) u16 wl[64 * 64];
    const uint4* gx = (const uint4*)(xhat + (size_t)n * TOKSZ);
    #pragma unroll
    for (int r = 0; r < 8; ++r) {
        int u = t + r * 256;
        int px = u >> 3, c8 = u & 7;
        *(uint4*)&xs[px * 72 + c8 * 8] = gx[u];
    }
    {
        const uint4* gw = (const uint4*)W116;
        #pragma unroll
        for (int r = 0; r < 2; ++r) { int u = t + r * 256; *(uint4*)&wl[u * 8] = gw[u]; }
    }
    __syncthreads();
    int px0 = wv * 64;
    // GEMM1: h = gelu(xhat @ W1^T + b1)
    {
        f32x4 acc[4][4];
        #pragma unroll
        for (int nt = 0; nt < 4; ++nt) {
            float b = b1[nt * 16 + m];
            #pragma unroll
            for (int mt = 0; mt < 4; ++mt) acc[mt][nt] = {b, b, b, b};
        }
        #pragma unroll
        for (int ks = 0; ks < 2; ++ks) {
            U8 af[4], bf[4];
            #pragma unroll
            for (int mt = 0; mt < 4; ++mt)
                af[mt].u = *(const uint4*)&xs[(px0 + mt * 16 + m) * 72 + ks * 32 + qd * 8];
            #pragma unroll
            for (int nt = 0; nt < 4; ++nt)
                bf[nt].u = *(const uint4*)&wl[(nt * 16 + m) * 64 + ks * 32 + qd * 8];
            #pragma unroll
            for (int mt = 0; mt < 4; ++mt) {
                #pragma unroll
                for (int nt = 0; nt < 4; ++nt)
                    acc[mt][nt] = __builtin_amdgcn_mfma_f32_16x16x32_bf16(
                        af[mt].b, bf[nt].b, acc[mt][nt], 0, 0, 0);
            }
        }
        #pragma unroll
        for (int nt = 0; nt < 4; ++nt) {
            int ch = nt * 16 + m;
            #pragma unroll
            for (int mt = 0; mt < 4; ++mt) {
                #pragma unroll
                for (int r = 0; r < 4; ++r) {
                    int px = px0 + mt * 16 + qd * 4 + r;
                    hs[px * 72 + ch] = f2bf(gelu_f(acc[mt][nt][r]));
                }
            }
        }
    }
    __syncthreads();                       // all B1 reads done -> restage wl
    {
        const uint4* gw = (const uint4*)W216;
        #pragma unroll
        for (int r = 0; r < 2; ++r) { int u = t + r * 256; *(uint4*)&wl[u * 8] = gw[u]; }
    }
    __syncthreads();
    // GEMM2: delta = h @ W2^T + b2 ; residual RMW
    {
        f32x4 acc[4][4];
        #pragma unroll
        for (int nt = 0; nt < 4; ++nt) {
            float b = b2[nt * 16 + m];
            #pragma unroll
            for (int mt = 0; mt < 4; ++mt) acc[mt][nt] = {b, b, b, b};
        }
        #pragma unroll
        for (int ks = 0; ks < 2; ++ks) {
            U8 af[4], bf[4];
            #pragma unroll
            for (int mt = 0; mt < 4; ++mt)
                af[mt].u = *(const uint4*)&hs[(px0 + mt * 16 + m) * 72 + ks * 32 + qd * 8];
            #pragma unroll
            for (int nt = 0; nt < 4; ++nt)
                bf[nt].u = *(const uint4*)&wl[(nt * 16 + m) * 64 + ks * 32 + qd * 8];
            #pragma unroll
            for (int mt = 0; mt < 4; ++mt) {
                #pragma unroll
                for (int nt = 0; nt < 4; ++nt)
                    acc[mt][nt] = __builtin_amdgcn_mfma_f32_16x16x32_bf16(
                        af[mt].b, bf[nt].b, acc[mt][nt], 0, 0, 0);
            }
        }
        float* dp = dres + (size_t)n * TOKSZ;
        #pragma unroll
        for (int nt = 0; nt < 4; ++nt) {
            int ch = nt * 16 + m;
            #pragma unroll
            for (int mt = 0; mt < 4; ++mt) {
                #pragma unroll
                for (int r = 0; r < 4; ++r) {
                    int px = px0 + mt * 16 + qd * 4 + r;
                    dp[px * 64 + ch] += acc[mt][nt][r];
                }
            }
        }
    }
}

// ---------------- fallback VALU kernels (hN < 4 paths) ---------------------
__global__ __launch_bounds__(256, 2)
void qkv_proj(const u16* __restrict__ xhat,
              const float* __restrict__ Wq, const float* __restrict__ bq,
              const float* __restrict__ Wk, const float* __restrict__ bk,
              const float* __restrict__ Wv, const float* __restrict__ bv,
              int hbase, int hN,
              u16* __restrict__ q, u16* __restrict__ k, u16* __restrict__ v) {
    int n = blockIdx.x, px = threadIdx.x;
    const uint4* xr = (const uint4*)(xhat + (size_t)n * TOKSZ + (size_t)px * 64);
    const float* Ws[3] = {Wq, Wk, Wv};
    const float* bs[3] = {bq, bk, bv};
    u16* outs[3] = {q, k, v};
    for (int ti = 0; ti < 3; ++ti) {
        const float* W = Ws[ti];
        const float* bb = bs[ti];
        for (int hh = 0; hh < hN; ++hh) {
            int h = hbase + hh;
            float acc[16];
            #pragma unroll
            for (int e2 = 0; e2 < 16; ++e2) acc[e2] = bb[h * 16 + e2];
            for (int c8 = 0; c8 < 8; ++c8) {
                uint4 xb = xr[c8];
                UNPACK8(xb, x0,x1,x2,x3,x4,x5,x6,x7)
                #pragma unroll
                for (int e2 = 0; e2 < 16; ++e2) {
                    const float* wr = W + (h * 16 + e2) * 64 + c8 * 8;
                    acc[e2] = fmaf(wr[0], x0, acc[e2]);
                    acc[e2] = fmaf(wr[1], x1, acc[e2]);
                    acc[e2] = fmaf(wr[2], x2, acc[e2]);
                    acc[e2] = fmaf(wr[3], x3, acc[e2]);
                    acc[e2] = fmaf(wr[4], x4, acc[e2]);
                    acc[e2] = fmaf(wr[5], x5, acc[e2]);
                    acc[e2] = fmaf(wr[6], x6, acc[e2]);
                    acc[e2] = fmaf(wr[7], x7, acc[e2]);
                }
            }
            uint4 o0, o1;
            o0.x = (u32)f2bf(acc[0])  | ((u32)f2bf(acc[1])  << 16);
            o0.y = (u32)f2bf(acc[2])  | ((u32)f2bf(acc[3])  << 16);
            o0.z = (u32)f2bf(acc[4])  | ((u32)f2bf(acc[5])  << 16);
            o0.w = (u32)f2bf(acc[6])  | ((u32)f2bf(acc[7])  << 16);
            o1.x = (u32)f2bf(acc[8])  | ((u32)f2bf(acc[9])  << 16);
            o1.y = (u32)f2bf(acc[10]) | ((u32)f2bf(acc[11]) << 16);
            o1.z = (u32)f2bf(acc[12]) | ((u32)f2bf(acc[13]) << 16);
            o1.w = (u32)f2bf(acc[14]) | ((u32)f2bf(acc[15]) << 16);
            uint4* op = (uint4*)(outs[ti] + ((size_t)hh * 2048 + n) * 4096 + (size_t)px * 16);
            op[0] = o0; op[1] = o1;
        }
    }
}

__global__ __launch_bounds__(256, 2)
void wo_accum(const u16* __restrict__ o, int hbase, int hN,
              const float* __restrict__ Wo, const float* __restrict__ bo,
              int shifted, float* __restrict__ dres) {
    int n = blockIdx.x, p = threadIdx.x;
    int no = shifted ? shift_tok(n) : n;
    float acc[64];
    if (hbase == 0) {
        #pragma unroll
        for (int e = 0; e < 64; ++e) acc[e] = bo[e];
    } else {
        #pragma unroll
        for (int e = 0; e < 64; ++e) acc[e] = 0.f;
    }
    for (int hh = 0; hh < hN; ++hh) {
        const uint4* op4 = (const uint4*)(o + ((size_t)hh * 2048 + n) * 4096 + (size_t)p * 16);
        float xv[16];
        {
            uint4 xb = op4[0];
            UNPACK8(xb, x0,x1,x2,x3,x4,x5,x6,x7)
            xv[0]=x0; xv[1]=x1; xv[2]=x2; xv[3]=x3; xv[4]=x4; xv[5]=x5; xv[6]=x6; xv[7]=x7;
        }
        {
            uint4 xb = op4[1];
            UNPACK8(xb, x0,x1,x2,x3,x4,x5,x6,x7)
            xv[8]=x0; xv[9]=x1; xv[10]=x2; xv[11]=x3; xv[12]=x4; xv[13]=x5; xv[14]=x6; xv[15]=x7;
        }
        int hc = (hbase + hh) * 16;
        #pragma unroll
        for (int c2 = 0; c2 < 16; ++c2) {
            #pragma unroll
            for (int e = 0; e < 64; ++e)
                acc[e] = fmaf(Wo[e * 64 + hc + c2], xv[c2], acc[e]);
        }
    }
    float* dp = dres + (size_t)no * TOKSZ + (size_t)p * 64;
    #pragma unroll
    for (int e = 0; e < 64; ++e) dp[e] += acc[e];
}

// ---------------- output MLP (unchanged) -----------------------------------
__global__ __launch_bounds__(256, 2)
void out_mlp(const float* __restrict__ d,
             const float* __restrict__ W1, const float* __restrict__ b1,
             const float* __restrict__ W2, const float* __restrict__ b2,
             void* __restrict__ out, const int* __restrict__ flag) {
    int n = blockIdx.x, p = threadIdx.x;
    const float* dp = d + (size_t)n * TOKSZ + (size_t)p * 64;
    float xr[64];
    #pragma unroll
    for (int e = 0; e < 64; ++e) xr[e] = dp[e];
    float acc = b2[0];
    for (int hid = 0; hid < 128; ++hid) {
        float h = b1[hid];
        #pragma unroll
        for (int e = 0; e < 64; ++e) h = fmaf(W1[hid * 64 + e], xr[e], h);
        acc = fmaf(W2[hid], gelu_f(h), acc);
    }
    int w = n >> 4, s = n & 15;
    int b = w >> 4, wy = (w >> 2) & 3, wx = w & 3;
    int ty = s >> 2, tx = s & 3;
    int y = ((wy << 2) + ty) * 16 + (p >> 4);
    int x = ((wx << 2) + tx) * 16 + (p & 15);
    size_t oi = (size_t)b * 65536 + (size_t)y * 256 + (size_t)x;
    if (*flag) ((float*)out)[oi] = acc;
    else       ((u16*)out)[oi] = f2bf(acc);
}

// ---------------- host launch ----------------------------------------------
extern "C" void kernel_launch(void* const* d_in, const int* in_sizes, int n_in,
                              void* d_out, int out_size, void* d_ws, size_t ws_size,
                              hipStream_t stream) {
    (void)n_in; (void)out_size;
    const int* pdsy = (const int*)d_in[21];
    const int* pdsx = (const int*)d_in[22];

    char* wsb = (char*)d_ws;
    float* bufd  = (float*)wsb;                          // 128 MiB
    u16*   xhat  = (u16*)(wsb + 134217728ull);           // 64 MiB
    float* A     = (float*)(wsb + 201326592ull);         // 512 KiB
    float* wbuf  = (float*)(wsb + 201850880ull);         // 512 KiB fp32 weights
    int*   flag  = (int*)(wsb + 202375168ull);           // 4 KiB
    u16*   wbuf16= (u16*)(wsb + 202379264ull);           // 320 KiB bf16 weights
    size_t slabOff = 202706944ull;

    int hN; size_t slabB;
    if      (ws_size >= slabOff + 3ull * 67108864ull) { hN = 4; slabB = 67108864ull; }
    else if (ws_size >= slabOff + 3ull * 33554432ull) { hN = 2; slabB = 33554432ull; }
    else                                              { hN = 1; slabB = 16777216ull; }
    u16* qb = (u16*)(wsb + slabOff);
    u16* kb = (u16*)(wsb + slabOff + slabB);
    u16* vb = (u16*)(wsb + slabOff + 2 * slabB);
    u16* ob = qb;   // q dead after scores

    WArgs wa;
    int off[NWT + 1]; off[0] = 0;
    for (int i = 0; i < NWT; ++i) {
        wa.src[i] = d_in[i + 1];
        off[i + 1] = off[i] + in_sizes[i + 1];
        wa.off[i] = off[i];
    }
    wa.off[NWT] = off[NWT];

    detect_kernel<<<1, 64, 0, stream>>>((const u16*)d_in[1], flag);
    cvt_weights<<<(off[NWT] + 255) / 256, 256, 0, stream>>>(wa, flag, wbuf, wbuf16);

    const float* f_inpW1 = wbuf + off[0];
    const float* f_inpb1 = wbuf + off[1];
    const float* f_inpW2 = wbuf + off[2];
    const float* f_inpb2 = wbuf + off[3];
    const float* f_Wq = wbuf + off[4];   const float* f_bq = wbuf + off[5];
    const float* f_Wk = wbuf + off[6];   const float* f_bk = wbuf + off[7];
    const float* f_Wv = wbuf + off[8];   const float* f_bv = wbuf + off[9];
    const float* f_Wo = wbuf + off[10];  const float* f_bo = wbuf + off[11];
    const float* f_mW1 = wbuf + off[12]; const float* f_mb1 = wbuf + off[13];
    const float* f_mW2 = wbuf + off[14]; const float* f_mb2 = wbuf + off[15];
    const float* f_oW1 = wbuf + off[16]; const float* f_ob1 = wbuf + off[17];
    const float* f_oW2 = wbuf + off[18]; const float* f_ob2 = wbuf + off[19];
    const u16* h_Wq = wbuf16 + off[4];
    const u16* h_Wk = wbuf16 + off[6];
    const u16* h_Wv = wbuf16 + off[8];
    const u16* h_Wo = wbuf16 + off[10];
    const u16* h_mW1 = wbuf16 + off[12];
    const u16* h_mW2 = wbuf16 + off[14];

    embed_kernel<<<NTOK, 256, 0, stream>>>(d_in[0], flag, f_inpW1, f_inpb1,
                                           f_inpW2, f_inpb2, pdsy, pdsx, bufd);

    for (int l = 0; l < 4; ++l) {
        int sh = l & 1;
        norm_xhat<<<NTOK, 256, 0, stream>>>(bufd, xhat);
        if (hN == 4) {
            qkv_mfma<<<NTOK, 256, 0, stream>>>(xhat,
                h_Wq + l * 4096, f_bq + l * 64,
                h_Wk + l * 4096, f_bk + l * 64,
                h_Wv + l * 4096, f_bv + l * 64, qb, kb, vb);
            scores_mfma<<<dim3(128, 4), 256, 0, stream>>>(qb, kb, sh, 0, A);
            av_kernel<<<dim3(128, 4), 256, 0, stream>>>(vb, A, sh, 0, ob);
            wo_mfma<<<NTOK, 256, 0, stream>>>(ob, h_Wo + l * 4096, f_bo + l * 64,
                                              sh, bufd);
        } else {
            for (int hb2 = 0; hb2 < 4; hb2 += hN) {
                qkv_proj<<<NTOK, 256, 0, stream>>>(xhat,
                    f_Wq + l * 4096, f_bq + l * 64,
                    f_Wk + l * 4096, f_bk + l * 64,
                    f_Wv + l * 4096, f_bv + l * 64, hb2, hN, qb, kb, vb);
                scores_mfma<<<dim3(128, hN), 256, 0, stream>>>(qb, kb, sh, hb2, A);
                av_kernel<<<dim3(128, hN), 256, 0, stream>>>(vb, A, sh, hb2, ob);
                wo_accum<<<NTOK, 256, 0, stream>>>(ob, hb2, hN,
                    f_Wo + l * 4096, f_bo + l * 64, sh, bufd);
            }
        }
        norm_xhat<<<NTOK, 256, 0, stream>>>(bufd, xhat);
        mlp_mfma<<<NTOK, 256, 0, stream>>>(bufd, xhat,
            h_mW1 + l * 4096, f_mb1 + l * 64,
            h_mW2 + l * 4096, f_mb2 + l * 64);
    }

    out_mlp<<<NTOK, 256, 0, stream>>>(bufd, f_oW1, f_ob1, f_oW2, f_ob2, d_out, flag);
}

// Round 8
// 2470.495 us; speedup vs baseline: 9.2443x; 2.8039x over previous
//
#include <hip/hip_runtime.h>
#include <math.h>

typedef unsigned short u16;
typedef unsigned int   u32;
typedef __attribute__((ext_vector_type(8))) short bf16x8;
typedef __attribute__((ext_vector_type(4))) float f32x4;

// ---------------- problem constants ----------------------------------------
// B=8, H=W=256, E=64, HID=128, SUB=16, WS=4, NH=4, dh=16, L=4
// tokens: 2048; residual d [tok][256 px][64 ch] fp32 (ch fastest)
// q/k/v/o slabs: [tok][256 px][CW ch] bf16, CW=32 (one head-pair per pass)
#define NTOK  2048
#define TOKSZ 16384ull

#define CBAR() __asm__ __volatile__("" ::: "memory")

__device__ __forceinline__ float bf2f(u16 b) { return __uint_as_float(((u32)b) << 16); }
__device__ __forceinline__ u16 f2bf(float f) {
    u32 u = __float_as_uint(f);
    u += 0x7FFFu + ((u >> 16) & 1u);
    return (u16)(u >> 16);
}
__device__ __forceinline__ float gelu_f(float x) {
    return 0.5f * x * (1.0f + erff(x * 0.70710678118654752440f));
}
__device__ __forceinline__ int shift_tok(int n) {
    int w = n >> 4, s = n & 15;
    int b = w >> 4, wy = (w >> 2) & 3, wx = w & 3;
    int ty = s >> 2, tx = s & 3;
    int gy = ((wy << 2) + ty + 2) & 15;
    int gx = ((wx << 2) + tx + 2) & 15;
    int w2 = (b << 4) + ((gy >> 2) << 2) + (gx >> 2);
    int s2 = ((gy & 3) << 2) + (gx & 3);
    return (w2 << 4) + s2;
}

union U8 { uint4 u; bf16x8 b; };

// ---------------- dtype detection (proven) ---------------------------------
__global__ void detect_kernel(const u16* __restrict__ w1, int* __restrict__ flag) {
    int t = threadIdx.x, bad = 0;
    for (int i = t; i < 640; i += 64) {
        float ax = fabsf(bf2f(w1[i]));
        if (!(ax < 1e3f)) bad = 1;
    }
    unsigned long long m = __ballot(bad);
    if (t == 0) *flag = (m != 0ull) ? 1 : 0;
}

// ---------------- weights: bf16 for GEMMs, compact fp32 for small ----------
#define NWT 20
struct WArgs { const void* src[NWT]; int off16[NWT + 1]; int f32o[NWT]; };

__global__ __launch_bounds__(256)
void cvt_weights(WArgs a, const int* __restrict__ flag,
                 float* __restrict__ wbufA, u16* __restrict__ wbuf16) {
    int t = blockIdx.x * 256 + threadIdx.x;
    if (t >= a.off16[NWT]) return;
    int s = 0;
    while (a.off16[s + 1] <= t) ++s;
    int idx = t - a.off16[s];
    u16 raw; float v;
    if (*flag) { v = ((const float*)a.src[s])[idx]; raw = f2bf(v); }
    else       { raw = ((const u16*)a.src[s])[idx]; v = bf2f(raw); }
    wbuf16[t] = raw;
    if (a.f32o[s] >= 0) wbufA[a.f32o[s] + idx] = v;
}

// ---------------- embed: coords+3ch -> 128(gelu) -> 64, MFMA ---------------
__global__ __launch_bounds__(256, 3)
void embed_mfma(const void* __restrict__ vin, const int* __restrict__ flag,
                const float* __restrict__ W1, const float* __restrict__ b1,
                const u16* __restrict__ W2bf, const float* __restrict__ b2,
                const int* __restrict__ pdsy, const int* __restrict__ pdsx,
                float* __restrict__ d) {
    extern __shared__ char smem[];
    u16* hsT = (u16*)smem;             // [256][72]
    u16* wl  = (u16*)(smem + 36864);   // [64][64]
    int n = blockIdx.x, t = threadIdx.x;
    int wv = t >> 6, l = t & 63, m = l & 15, qd = l >> 4;
    int px0 = wv * 64;

    int w = n >> 4, s = n & 15;
    int b = w >> 4, wy = (w >> 2) & 3, wx = w & 3;
    int ty = s >> 2, tx = s & 3;
    int y = ((wy << 2) + ty) * 16 + (t >> 4);
    int x = ((wx << 2) + tx) * 16 + (t & 15);
    int fl = *flag;
    float in0 = ((float)y + 0.5f) * ((float)pdsy[0] * (1.0f / 256.0f));
    float in1 = ((float)x + 0.5f) * ((float)pdsx[0] * (1.0f / 256.0f));
    size_t pix = (size_t)b * 3 * 65536 + (size_t)y * 256 + (size_t)x;
    float in2 = fl ? ((const float*)vin)[pix]          : bf2f(((const u16*)vin)[pix]);
    float in3 = fl ? ((const float*)vin)[pix + 65536]  : bf2f(((const u16*)vin)[pix + 65536]);
    float in4 = fl ? ((const float*)vin)[pix + 131072] : bf2f(((const u16*)vin)[pix + 131072]);

    f32x4 acc[4][4];
    #pragma unroll
    for (int nt = 0; nt < 4; ++nt) {
        float bb = b2[nt * 16 + m];
        #pragma unroll
        for (int mt = 0; mt < 4; ++mt) acc[mt][nt] = {bb, bb, bb, bb};
    }
    for (int half = 0; half < 2; ++half) {
        if (half) __syncthreads();
        for (int h2 = 0; h2 < 64; h2 += 2) {
            int hid = half * 64 + h2;
            float ha = b1[hid] + W1[hid*5]*in0 + W1[hid*5+1]*in1 + W1[hid*5+2]*in2
                     + W1[hid*5+3]*in3 + W1[hid*5+4]*in4;
            float hb2 = b1[hid+1] + W1[hid*5+5]*in0 + W1[hid*5+6]*in1 + W1[hid*5+7]*in2
                     + W1[hid*5+8]*in3 + W1[hid*5+9]*in4;
            u32 pk = (u32)f2bf(gelu_f(ha)) | ((u32)f2bf(gelu_f(hb2)) << 16);
            *(u32*)&hsT[t * 72 + h2] = pk;
        }
        #pragma unroll
        for (int r = 0; r < 2; ++r) {
            int u = t + r * 256; int e = u >> 3, c8 = u & 7;
            *(uint4*)&wl[(e << 6) + c8 * 8] = *(const uint4*)(W2bf + e * 128 + half * 64 + c8 * 8);
        }
        __syncthreads();
        #pragma unroll
        for (int ks = 0; ks < 2; ++ks) {
            U8 af[4], bf[4];
            #pragma unroll
            for (int mt = 0; mt < 4; ++mt)
                af[mt].u = *(const uint4*)&hsT[(px0 + mt*16 + m) * 72 + ks*32 + qd*8];
            #pragma unroll
            for (int nt = 0; nt < 4; ++nt)
                bf[nt].u = *(const uint4*)&wl[(nt*16 + m) * 64 + ks*32 + qd*8];
            #pragma unroll
            for (int mt = 0; mt < 4; ++mt)
                #pragma unroll
                for (int nt = 0; nt < 4; ++nt)
                    acc[mt][nt] = __builtin_amdgcn_mfma_f32_16x16x32_bf16(
                        af[mt].b, bf[nt].b, acc[mt][nt], 0, 0, 0);
        }
    }
    __syncthreads();
    float* eps = (float*)smem + wv * 2304;
    float* dp = d + (size_t)n * TOKSZ;
    #pragma unroll
    for (int ch2 = 0; ch2 < 2; ++ch2) {
        if (ch2) CBAR();
        #pragma unroll
        for (int mt = ch2*2; mt < ch2*2+2; ++mt)
            #pragma unroll
            for (int nt = 0; nt < 4; ++nt)
                #pragma unroll
                for (int r = 0; r < 4; ++r)
                    eps[((mt&1)*16 + qd*4 + r) * 68 + nt*16 + m] = acc[mt][nt][r];
        CBAR();
        #pragma unroll
        for (int j = 0; j < 8; ++j) {
            int f = l + 64*j; int row = f >> 4, c4 = f & 15;
            float4 v = *(float4*)&eps[row * 68 + c4 * 4];
            *(float4*)&dp[(px0 + ch2*32 + row) * 64 + c4 * 4] = v;
        }
    }
}

// ---------------- fused norm + projection (NW matrices, CW/16 heads) -------
template<int CW, int NW>
__global__ __launch_bounds__(256, 2)
void proj_kernel(const float* __restrict__ d,
                 const u16* __restrict__ Wa, const float* __restrict__ ba,
                 const u16* __restrict__ Wb, const float* __restrict__ bbp,
                 int hbase,
                 u16* __restrict__ oa, u16* __restrict__ obp) {
    constexpr int HN = CW / 16;
    extern __shared__ char smem[];
    u16* xs = (u16*)smem;                      // [256][72]
    u16* wl = (u16*)(smem + 36864);            // up to [64][64]
    float* sarr = (float*)(smem + 36864);      // alias, stats phase
    float* murs = (float*)(smem + 45056);      // 512 B
    u16* ep = (u16*)(smem + 45568);            // 4 * 32*(CW+8) u16
    int n = blockIdx.x, t = threadIdx.x;
    const float4* gin = (const float4*)(d + (size_t)n * TOKSZ);
    int cb = (4 * t) & 63, g = t >> 4;
    float4 xv[16];
    float s0=0,s1=0,s2=0,s3=0,q0=0,q1=0,q2=0,q3=0;
    #pragma unroll
    for (int r = 0; r < 16; ++r) {
        float4 v = gin[t + r * 256]; xv[r] = v;
        s0 += v.x; q0 = fmaf(v.x, v.x, q0);
        s1 += v.y; q1 = fmaf(v.y, v.y, q1);
        s2 += v.z; q2 = fmaf(v.z, v.z, q2);
        s3 += v.w; q3 = fmaf(v.w, v.w, q3);
    }
    sarr[(cb+0)*16+g]=s0; sarr[(cb+1)*16+g]=s1; sarr[(cb+2)*16+g]=s2; sarr[(cb+3)*16+g]=s3;
    float* qarr = sarr + 1024;
    qarr[(cb+0)*16+g]=q0; qarr[(cb+1)*16+g]=q1; qarr[(cb+2)*16+g]=q2; qarr[(cb+3)*16+g]=q3;
    __syncthreads();
    if (t < 64) {
        float ss = 0.f, qq = 0.f;
        #pragma unroll
        for (int gg = 0; gg < 16; ++gg) { ss += sarr[t*16+gg]; qq += qarr[t*16+gg]; }
        float mu = ss * (1.0f/256.0f);
        float var = qq * (1.0f/256.0f) - mu * mu;
        murs[t] = mu; murs[64 + t] = rsqrtf(var + 1e-5f);
    }
    __syncthreads();
    {
        float m0 = murs[cb], m1 = murs[cb+1], m2 = murs[cb+2], m3 = murs[cb+3];
        float r0 = murs[64+cb], r1 = murs[64+cb+1], r2 = murs[64+cb+2], r3 = murs[64+cb+3];
        #pragma unroll
        for (int r = 0; r < 16; ++r) {
            float4 v = xv[r];
            int px = (t >> 4) + r * 16;
            uint2 o;
            o.x = (u32)f2bf((v.x-m0)*r0) | ((u32)f2bf((v.y-m1)*r1) << 16);
            o.y = (u32)f2bf((v.z-m2)*r2) | ((u32)f2bf((v.w-m3)*r3) << 16);
            *(uint2*)&xs[px * 72 + cb] = o;
        }
    }
    int wv = t >> 6, l = t & 63, m = l & 15, qd = l >> 4;
    int px0 = wv * 64;
    const u16* Ws[2] = {Wa, Wb};
    const float* bs[2] = {ba, bbp};
    u16* outs[2] = {oa, obp};
    for (int ti = 0; ti < NW; ++ti) {
        if (ti) __syncthreads();
        for (int u = t; u < HN * 128; u += 256) {
            int e = u >> 3, c8 = u & 7;
            *(uint4*)&wl[e * 64 + c8 * 8] =
                *(const uint4*)(Ws[ti] + (size_t)(hbase * 16 + e) * 64 + c8 * 8);
        }
        __syncthreads();
        f32x4 acc[4][HN];
        #pragma unroll
        for (int nt = 0; nt < HN; ++nt) {
            float bb = bs[ti][hbase * 16 + nt * 16 + m];
            #pragma unroll
            for (int mt = 0; mt < 4; ++mt) acc[mt][nt] = {bb, bb, bb, bb};
        }
        #pragma unroll
        for (int ks = 0; ks < 2; ++ks) {
            U8 af[4], bf[HN];
            #pragma unroll
            for (int mt = 0; mt < 4; ++mt)
                af[mt].u = *(const uint4*)&xs[(px0 + mt*16 + m) * 72 + ks*32 + qd*8];
            #pragma unroll
            for (int nt = 0; nt < HN; ++nt)
                bf[nt].u = *(const uint4*)&wl[(nt*16 + m) * 64 + ks*32 + qd*8];
            #pragma unroll
            for (int mt = 0; mt < 4; ++mt)
                #pragma unroll
                for (int nt = 0; nt < HN; ++nt)
                    acc[mt][nt] = __builtin_amdgcn_mfma_f32_16x16x32_bf16(
                        af[mt].b, bf[nt].b, acc[mt][nt], 0, 0, 0);
        }
        u16* epw = ep + wv * (32 * (CW + 8));
        u16* dst0 = outs[ti] + (size_t)n * 256 * CW;
        #pragma unroll
        for (int ch2 = 0; ch2 < 2; ++ch2) {
            if (ch2) CBAR();
            #pragma unroll
            for (int mt = ch2*2; mt < ch2*2+2; ++mt)
                #pragma unroll
                for (int nt = 0; nt < HN; ++nt)
                    #pragma unroll
                    for (int r = 0; r < 4; ++r)
                        epw[((mt&1)*16 + qd*4 + r) * (CW+8) + nt*16 + m] = f2bf(acc[mt][nt][r]);
            CBAR();
            #pragma unroll
            for (int u = l; u < 32 * (CW/8); u += 64) {
                int row = u / (CW/8), c8 = u % (CW/8);
                *(uint4*)(dst0 + (size_t)(px0 + ch2*32 + row) * CW + c8*8)
                    = *(uint4*)&epw[row * (CW+8) + c8*8];
            }
        }
    }
}

// ---------------- scores via MFMA + softmax --------------------------------
template<int CW>
__global__ __launch_bounds__(256, 4)
void scores_mfma(const u16* __restrict__ q, const u16* __restrict__ k,
                 int shifted, int hbase, float* __restrict__ A) {
    int w = blockIdx.x, hy = blockIdx.y, t = threadIdx.x;
    int wv = t >> 6, l = t & 63, m = l & 15, qd = l >> 4;
    int n0 = w * 16 + m;
    int ni = shifted ? shift_tok(n0) : n0;
    size_t base = (size_t)ni * 256 * CW + hy * 16 + (qd & 1) * 8;
    const u16* qrow = q + base;
    const u16* krow = k + base;
    int pxb = wv * 64 + (qd >> 1);
    f32x4 acc = {0.f, 0.f, 0.f, 0.f};
    for (int s = 0; s < 32; ++s) {
        U8 qa, kv;
        qa.u = *(const uint4*)(qrow + (size_t)(pxb + s*2) * CW);
        kv.u = *(const uint4*)(krow + (size_t)(pxb + s*2) * CW);
        acc = __builtin_amdgcn_mfma_f32_16x16x32_bf16(qa.b, kv.b, acc, 0, 0, 0);
    }
    __shared__ float pc[4][256];
    #pragma unroll
    for (int r = 0; r < 4; ++r) pc[wv][l * 4 + r] = acc[r];
    __syncthreads();
    if (wv == 0) {
        float* arow = A + ((size_t)(w * 4 + hbase + hy) * 16) * 16;
        #pragma unroll
        for (int r = 0; r < 4; ++r) {
            float sc = (pc[0][l*4+r] + pc[1][l*4+r] + pc[2][l*4+r] + pc[3][l*4+r])
                     * (1.0f / 1024.0f);
            float mx = sc;
            #pragma unroll
            for (int off = 1; off < 16; off <<= 1) mx = fmaxf(mx, __shfl_xor(mx, off, 16));
            float e = expf(sc - mx);
            float ssum = e;
            #pragma unroll
            for (int off = 1; off < 16; off <<= 1) ssum += __shfl_xor(ssum, off, 16);
            arow[(qd * 4 + r) * 16 + m] = e / ssum;
        }
    }
}

// ---------------- o = A @ v ------------------------------------------------
template<int CW>
__global__ __launch_bounds__(256, 4)
void av_kernel(const u16* __restrict__ v, const float* __restrict__ A,
               int shifted, int hbase, u16* __restrict__ o) {
    int w = blockIdx.x, hy = blockIdx.y, t = threadIdx.x;
    __shared__ int nis[16];
    __shared__ float As[256];
    if (t < 16) { int n = w * 16 + t; nis[t] = shifted ? shift_tok(n) : n; }
    As[t] = A[(size_t)(w * 4 + hbase + hy) * 256 + t];
    __syncthreads();
    for (int cc = 0; cc < 8; ++cc) {
        int idx2 = cc * 256 + t;
        int px = idx2 >> 3, cp = (idx2 & 7) * 2;
        int off = px * CW + hy * 16 + cp;
        float v0[16], v1[16];
        #pragma unroll
        for (int j = 0; j < 16; ++j) {
            u32 pv = *(const u32*)(v + (size_t)nis[j] * 256 * CW + off);
            v0[j] = __uint_as_float(pv << 16);
            v1[j] = __uint_as_float(pv & 0xFFFF0000u);
        }
        #pragma unroll
        for (int i = 0; i < 16; ++i) {
            float a0 = 0.f, a1 = 0.f;
            #pragma unroll
            for (int j = 0; j < 16; ++j) {
                float aw = As[i * 16 + j];
                a0 = fmaf(aw, v0[j], a0);
                a1 = fmaf(aw, v1[j], a1);
            }
            *(u32*)(o + (size_t)(w * 16 + i) * 256 * CW + off)
                = (u32)f2bf(a0) | ((u32)f2bf(a1) << 16);
        }
    }
}

// ---------------- Wo MFMA (K=64 from 1 or 2 slabs) + residual RMW ----------
template<int CW>
__global__ __launch_bounds__(256, 3)
void wo_mfma(const u16* __restrict__ o1, const u16* __restrict__ o2,
             const u16* __restrict__ Wo, const float* __restrict__ bo,
             int shifted, float* __restrict__ dres) {
    extern __shared__ char smem[];
    u16* xs = (u16*)smem;              // [256][72]
    u16* wl = (u16*)(smem + 36864);    // [64][64]
    int n = blockIdx.x, t = threadIdx.x;
    int wv = t >> 6, l = t & 63, m = l & 15, qd = l >> 4;
    int px0 = wv * 64;
    int no = shifted ? shift_tok(n) : n;
    #pragma unroll
    for (int r = 0; r < 8; ++r) {
        int u = t + r * 256;
        int px = u >> 3, c8 = u & 7;
        const u16* src;
        if (CW == 64) src = o1 + (size_t)n * 16384 + px * 64 + c8 * 8;
        else src = (c8 < 4) ? (o1 + (size_t)n * 8192 + px * 32 + c8 * 8)
                            : (o2 + (size_t)n * 8192 + px * 32 + (c8 - 4) * 8);
        *(uint4*)&xs[px * 72 + c8 * 8] = *(const uint4*)src;
    }
    #pragma unroll
    for (int r = 0; r < 2; ++r) {
        int u = t + r * 256;
        *(uint4*)&wl[u * 8] = *(const uint4*)(Wo + u * 8);
    }
    __syncthreads();
    f32x4 acc[4][4];
    #pragma unroll
    for (int nt = 0; nt < 4; ++nt) {
        float bb = bo[nt * 16 + m];
        #pragma unroll
        for (int mt = 0; mt < 4; ++mt) acc[mt][nt] = {bb, bb, bb, bb};
    }
    #pragma unroll
    for (int ks = 0; ks < 2; ++ks) {
        U8 af[4], bf[4];
        #pragma unroll
        for (int mt = 0; mt < 4; ++mt)
            af[mt].u = *(const uint4*)&xs[(px0 + mt*16 + m) * 72 + ks*32 + qd*8];
        #pragma unroll
        for (int nt = 0; nt < 4; ++nt)
            bf[nt].u = *(const uint4*)&wl[(nt*16 + m) * 64 + ks*32 + qd*8];
        #pragma unroll
        for (int mt = 0; mt < 4; ++mt)
            #pragma unroll
            for (int nt = 0; nt < 4; ++nt)
                acc[mt][nt] = __builtin_amdgcn_mfma_f32_16x16x32_bf16(
                    af[mt].b, bf[nt].b, acc[mt][nt], 0, 0, 0);
    }
    __syncthreads();                     // all xs/wl reads done -> alias eps
    float* eps = (float*)smem + wv * 2304;
    float* dp = dres + (size_t)no * TOKSZ;
    #pragma unroll
    for (int ch2 = 0; ch2 < 2; ++ch2) {
        if (ch2) CBAR();
        #pragma unroll
        for (int mt = ch2*2; mt < ch2*2+2; ++mt)
            #pragma unroll
            for (int nt = 0; nt < 4; ++nt)
                #pragma unroll
                for (int r = 0; r < 4; ++r)
                    eps[((mt&1)*16 + qd*4 + r) * 68 + nt*16 + m] = acc[mt][nt][r];
        CBAR();
        #pragma unroll
        for (int j = 0; j < 8; ++j) {
            int f = l + 64*j; int row = f >> 4, c4 = f & 15;
            float4 dv = *(float4*)&eps[row * 68 + c4 * 4];
            float* gp = &dp[(px0 + ch2*32 + row) * 64 + c4 * 4];
            float4 gv = *(float4*)gp;
            gv.x += dv.x; gv.y += dv.y; gv.z += dv.z; gv.w += dv.w;
            *(float4*)gp = gv;
        }
    }
}

// ---------------- fused norm + MLP (two MFMA GEMMs) + residual -------------
__global__ __launch_bounds__(256, 2)
void mlp_fused(float* __restrict__ dres,
               const u16* __restrict__ W1, const float* __restrict__ b1,
               const u16* __restrict__ W2, const float* __restrict__ b2) {
    extern __shared__ char smem[];
    u16* xs = (u16*)smem;
    u16* wl = (u16*)(smem + 36864);
    float* sarr = (float*)(smem + 36864);
    float* murs = (float*)(smem + 45056);
    int n = blockIdx.x, t = threadIdx.x;
    const float4* gin = (const float4*)(dres + (size_t)n * TOKSZ);
    int cb = (4 * t) & 63, g = t >> 4;
    float4 xv[16];
    float s0=0,s1=0,s2=0,s3=0,q0=0,q1=0,q2=0,q3=0;
    #pragma unroll
    for (int r = 0; r < 16; ++r) {
        float4 v = gin[t + r * 256]; xv[r] = v;
        s0 += v.x; q0 = fmaf(v.x, v.x, q0);
        s1 += v.y; q1 = fmaf(v.y, v.y, q1);
        s2 += v.z; q2 = fmaf(v.z, v.z, q2);
        s3 += v.w; q3 = fmaf(v.w, v.w, q3);
    }
    sarr[(cb+0)*16+g]=s0; sarr[(cb+1)*16+g]=s1; sarr[(cb+2)*16+g]=s2; sarr[(cb+3)*16+g]=s3;
    float* qarr = sarr + 1024;
    qarr[(cb+0)*16+g]=q0; qarr[(cb+1)*16+g]=q1; qarr[(cb+2)*16+g]=q2; qarr[(cb+3)*16+g]=q3;
    __syncthreads();
    if (t < 64) {
        float ss = 0.f, qq = 0.f;
        #pragma unroll
        for (int gg = 0; gg < 16; ++gg) { ss += sarr[t*16+gg]; qq += qarr[t*16+gg]; }
        float mu = ss * (1.0f/256.0f);
        float var = qq * (1.0f/256.0f) - mu * mu;
        murs[t] = mu; murs[64 + t] = rsqrtf(var + 1e-5f);
    }
    __syncthreads();
    {
        float m0 = murs[cb], m1 = murs[cb+1], m2 = murs[cb+2], m3 = murs[cb+3];
        float r0 = murs[64+cb], r1 = murs[64+cb+1], r2 = murs[64+cb+2], r3 = murs[64+cb+3];
        #pragma unroll
        for (int r = 0; r < 16; ++r) {
            float4 v = xv[r];
            int px = (t >> 4) + r * 16;
            uint2 o;
            o.x = (u32)f2bf((v.x-m0)*r0) | ((u32)f2bf((v.y-m1)*r1) << 16);
            o.y = (u32)f2bf((v.z-m2)*r2) | ((u32)f2bf((v.w-m3)*r3) << 16);
            *(uint2*)&xs[px * 72 + cb] = o;
        }
    }
    int wv = t >> 6, l = t & 63, m = l & 15, qd = l >> 4;
    int px0 = wv * 64;
    #pragma unroll
    for (int r = 0; r < 2; ++r) {
        int u = t + r * 256;
        *(uint4*)&wl[u * 8] = *(const uint4*)(W1 + u * 8);
    }
    __syncthreads();
    f32x4 acc[4][4];
    #pragma unroll
    for (int nt = 0; nt < 4; ++nt) {
        float bb = b1[nt * 16 + m];
        #pragma unroll
        for (int mt = 0; mt < 4; ++mt) acc[mt][nt] = {bb, bb, bb, bb};
    }
    #pragma unroll
    for (int ks = 0; ks < 2; ++ks) {
        U8 af[4], bf[4];
        #pragma unroll
        for (int mt = 0; mt < 4; ++mt)
            af[mt].u = *(const uint4*)&xs[(px0 + mt*16 + m) * 72 + ks*32 + qd*8];
        #pragma unroll
        for (int nt = 0; nt < 4; ++nt)
            bf[nt].u = *(const uint4*)&wl[(nt*16 + m) * 64 + ks*32 + qd*8];
        #pragma unroll
        for (int mt = 0; mt < 4; ++mt)
            #pragma unroll
            for (int nt = 0; nt < 4; ++nt)
                acc[mt][nt] = __builtin_amdgcn_mfma_f32_16x16x32_bf16(
                    af[mt].b, bf[nt].b, acc[mt][nt], 0, 0, 0);
    }
    __syncthreads();
    #pragma unroll
    for (int nt = 0; nt < 4; ++nt) {
        int ch = nt * 16 + m;
        #pragma unroll
        for (int mt = 0; mt < 4; ++mt)
            #pragma unroll
            for (int r = 0; r < 4; ++r)
                xs[(px0 + mt*16 + qd*4 + r) * 72 + ch] = f2bf(gelu_f(acc[mt][nt][r]));
    }
    #pragma unroll
    for (int r = 0; r < 2; ++r) {
        int u = t + r * 256;
        *(uint4*)&wl[u * 8] = *(const uint4*)(W2 + u * 8);
    }
    __syncthreads();
    #pragma unroll
    for (int nt = 0; nt < 4; ++nt) {
        float bb = b2[nt * 16 + m];
        #pragma unroll
        for (int mt = 0; mt < 4; ++mt) acc[mt][nt] = {bb, bb, bb, bb};
    }
    #pragma unroll
    for (int ks = 0; ks < 2; ++ks) {
        U8 af[4], bf[4];
        #pragma unroll
        for (int mt = 0; mt < 4; ++mt)
            af[mt].u = *(const uint4*)&xs[(px0 + mt*16 + m) * 72 + ks*32 + qd*8];
        #pragma unroll
        for (int nt = 0; nt < 4; ++nt)
            bf[nt].u = *(const uint4*)&wl[(nt*16 + m) * 64 + ks*32 + qd*8];
        #pragma unroll
        for (int mt = 0; mt < 4; ++mt)
            #pragma unroll
            for (int nt = 0; nt < 4; ++nt)
                acc[mt][nt] = __builtin_amdgcn_mfma_f32_16x16x32_bf16(
                    af[mt].b, bf[nt].b, acc[mt][nt], 0, 0, 0);
    }
    __syncthreads();
    float* eps = (float*)smem + wv * 2304;
    float* dp = dres + (size_t)n * TOKSZ;
    #pragma unroll
    for (int ch2 = 0; ch2 < 2; ++ch2) {
        if (ch2) CBAR();
        #pragma unroll
        for (int mt = ch2*2; mt < ch2*2+2; ++mt)
            #pragma unroll
            for (int nt = 0; nt < 4; ++nt)
                #pragma unroll
                for (int r = 0; r < 4; ++r)
                    eps[((mt&1)*16 + qd*4 + r) * 68 + nt*16 + m] = acc[mt][nt][r];
        CBAR();
        #pragma unroll
        for (int j = 0; j < 8; ++j) {
            int f = l + 64*j; int row = f >> 4, c4 = f & 15;
            float4 dv = *(float4*)&eps[row * 68 + c4 * 4];
            float* gp = &dp[(px0 + ch2*32 + row) * 64 + c4 * 4];
            float4 gv = *(float4*)gp;
            gv.x += dv.x; gv.y += dv.y; gv.z += dv.z; gv.w += dv.w;
            *(float4*)gp = gv;
        }
    }
}

// ---------------- output MLP via MFMA: 64 -> 128(gelu) -> 1 ----------------
__global__ __launch_bounds__(256, 3)
void out_mfma(const float* __restrict__ d,
              const u16* __restrict__ W1, const float* __restrict__ b1,
              const float* __restrict__ W2, const float* __restrict__ b2,
              void* __restrict__ out, const int* __restrict__ flag) {
    extern __shared__ char smem[];
    u16* xs = (u16*)smem;
    u16* wl = (u16*)(smem + 36864);
    int n = blockIdx.x, t = threadIdx.x;
    int wv = t >> 6, l = t & 63, m = l & 15, qd = l >> 4;
    int px0 = wv * 64;
    const float4* gin = (const float4*)(d + (size_t)n * TOKSZ);
    #pragma unroll
    for (int r = 0; r < 16; ++r) {
        float4 xv = gin[t + r * 256];
        int fi = (t + r * 256) * 4;
        int px = fi >> 6, ch = fi & 63;
        uint2 o;
        o.x = (u32)f2bf(xv.x) | ((u32)f2bf(xv.y) << 16);
        o.y = (u32)f2bf(xv.z) | ((u32)f2bf(xv.w) << 16);
        *(uint2*)&xs[px * 72 + ch] = o;
    }
    float val[4][4];
    #pragma unroll
    for (int mt = 0; mt < 4; ++mt)
        #pragma unroll
        for (int r = 0; r < 4; ++r) val[mt][r] = 0.f;
    for (int nh = 0; nh < 2; ++nh) {
        if (nh) __syncthreads();
        #pragma unroll
        for (int r = 0; r < 2; ++r) {
            int u = t + r * 256;
            *(uint4*)&wl[u * 8] = *(const uint4*)(W1 + (size_t)nh * 4096 + u * 8);
        }
        __syncthreads();
        f32x4 acc[4][4];
        #pragma unroll
        for (int nt = 0; nt < 4; ++nt) {
            float bb = b1[nh * 64 + nt * 16 + m];
            #pragma unroll
            for (int mt = 0; mt < 4; ++mt) acc[mt][nt] = {bb, bb, bb, bb};
        }
        #pragma unroll
        for (int ks = 0; ks < 2; ++ks) {
            U8 af[4], bf[4];
            #pragma unroll
            for (int mt = 0; mt < 4; ++mt)
                af[mt].u = *(const uint4*)&xs[(px0 + mt*16 + m) * 72 + ks*32 + qd*8];
            #pragma unroll
            for (int nt = 0; nt < 4; ++nt)
                bf[nt].u = *(const uint4*)&wl[(nt*16 + m) * 64 + ks*32 + qd*8];
            #pragma unroll
            for (int mt = 0; mt < 4; ++mt)
                #pragma unroll
                for (int nt = 0; nt < 4; ++nt)
                    acc[mt][nt] = __builtin_amdgcn_mfma_f32_16x16x32_bf16(
                        af[mt].b, bf[nt].b, acc[mt][nt], 0, 0, 0);
        }
        float w2v[4];
        #pragma unroll
        for (int nt = 0; nt < 4; ++nt) w2v[nt] = W2[nh * 64 + nt * 16 + m];
        #pragma unroll
        for (int mt = 0; mt < 4; ++mt)
            #pragma unroll
            for (int r = 0; r < 4; ++r) {
                float p = 0.f;
                #pragma unroll
                for (int nt = 0; nt < 4; ++nt)
                    p = fmaf(gelu_f(acc[mt][nt][r]), w2v[nt], p);
                val[mt][r] += p;
            }
    }
    __syncthreads();
    float* red = (float*)smem;
    #pragma unroll
    for (int mt = 0; mt < 4; ++mt)
        #pragma unroll
        for (int r = 0; r < 4; ++r)
            red[(px0 + mt*16 + qd*4 + r) * 17 + m] = val[mt][r];
    __syncthreads();
    float a = b2[0];
    #pragma unroll
    for (int j = 0; j < 16; ++j) a += red[t * 17 + j];
    int w = n >> 4, s = n & 15;
    int b = w >> 4, wy = (w >> 2) & 3, wx = w & 3;
    int ty = s >> 2, tx = s & 3;
    int y = ((wy << 2) + ty) * 16 + (t >> 4);
    int x = ((wx << 2) + tx) * 16 + (t & 15);
    size_t oi = (size_t)b * 65536 + (size_t)y * 256 + (size_t)x;
    if (*flag) ((float*)out)[oi] = a;
    else       ((u16*)out)[oi] = f2bf(a);
}

// ---------------- host launch ----------------------------------------------
extern "C" void kernel_launch(void* const* d_in, const int* in_sizes, int n_in,
                              void* d_out, int out_size, void* d_ws, size_t ws_size,
                              hipStream_t stream) {
    (void)n_in; (void)out_size; (void)ws_size;
    const int* pdsy = (const int*)d_in[21];
    const int* pdsx = (const int*)d_in[22];

    // layout (bytes), total 235.65 MB < proven 235.93 MB envelope:
    // bufd 134217728 | qb 33554432 | kb 33554432 | vb 33554432 |
    // A 524288 | wbufA 10752 | wbuf16 234752 | flag 4096
    char* wsb = (char*)d_ws;
    float* bufd = (float*)wsb;
    u16* qb = (u16*)(wsb + 134217728ull);
    u16* kb = (u16*)(wsb + 167772160ull);
    u16* vb = (u16*)(wsb + 201326592ull);
    float* A     = (float*)(wsb + 234881024ull);
    float* wbufA = (float*)(wsb + 235405312ull);
    u16* wbuf16  = (u16*)(wsb + 235416064ull);
    int* flag    = (int*)(wsb + 235650816ull);

    // d_in indices needing fp32 (biases + small MLP pieces)
    const int f32set[12] = {1, 2, 4, 6, 8, 10, 12, 14, 16, 18, 19, 20};
    WArgs wa;
    int off16[NWT + 1]; off16[0] = 0;
    int c32[NWT + 1];
    int fo = 0;
    for (int i = 0; i < NWT; ++i) {
        int di = i + 1;
        wa.src[i] = d_in[di];
        off16[i + 1] = off16[i] + in_sizes[di];
        wa.off16[i] = off16[i];
        int isf = 0;
        for (int j = 0; j < 12; ++j) if (f32set[j] == di) isf = 1;
        wa.f32o[i] = isf ? fo : -1;
        c32[di] = isf ? fo : -1;
        if (isf) fo += in_sizes[di];
    }
    wa.off16[NWT] = off16[NWT];

    detect_kernel<<<1, 64, 0, stream>>>((const u16*)d_in[1], flag);
    cvt_weights<<<(off16[NWT] + 255) / 256, 256, 0, stream>>>(wa, flag, wbufA, wbuf16);

    const float* f_inpW1 = wbufA + c32[1];
    const float* f_inpb1 = wbufA + c32[2];
    const float* f_inpb2 = wbufA + c32[4];
    const float* f_bq  = wbufA + c32[6];
    const float* f_bk  = wbufA + c32[8];
    const float* f_bv  = wbufA + c32[10];
    const float* f_bo  = wbufA + c32[12];
    const float* f_mb1 = wbufA + c32[14];
    const float* f_mb2 = wbufA + c32[16];
    const float* f_ob1 = wbufA + c32[18];
    const float* f_oW2 = wbufA + c32[19];
    const float* f_ob2 = wbufA + c32[20];
    const u16* h_inpW2 = wbuf16 + off16[2];   // d_in[3]
    const u16* h_Wq  = wbuf16 + off16[4];     // d_in[5]
    const u16* h_Wk  = wbuf16 + off16[6];
    const u16* h_Wv  = wbuf16 + off16[8];
    const u16* h_Wo  = wbuf16 + off16[10];
    const u16* h_mW1 = wbuf16 + off16[12];
    const u16* h_mW2 = wbuf16 + off16[14];
    const u16* h_oW1 = wbuf16 + off16[16];

    embed_mfma<<<NTOK, 256, 45056, stream>>>(d_in[0], flag, f_inpW1, f_inpb1,
                                             h_inpW2, f_inpb2, pdsy, pdsx, bufd);

    for (int l = 0; l < 4; ++l) {
        int sh = l & 1;
        const u16* Wql = h_Wq + l * 4096;  const float* bql = f_bq + l * 64;
        const u16* Wkl = h_Wk + l * 4096;  const float* bkl = f_bk + l * 64;
        const u16* Wvl = h_Wv + l * 4096;  const float* bvl = f_bv + l * 64;
        const u16* Wol = h_Wo + l * 4096;  const float* bol = f_bo + l * 64;
        const u16* W1l = h_mW1 + l * 4096; const float* b1l = f_mb1 + l * 64;
        const u16* W2l = h_mW2 + l * 4096; const float* b2l = f_mb2 + l * 64;

        // q,k for head-pairs; scores; then v + A@v; wo once (bufd mutated last)
        proj_kernel<32, 2><<<NTOK, 256, 64000, stream>>>(bufd, Wql, bql, Wkl, bkl, 0, qb, kb);
        scores_mfma<32><<<dim3(128, 2), 256, 0, stream>>>(qb, kb, sh, 0, A);
        proj_kernel<32, 2><<<NTOK, 256, 64000, stream>>>(bufd, Wql, bql, Wkl, bkl, 2, qb, kb);
        scores_mfma<32><<<dim3(128, 2), 256, 0, stream>>>(qb, kb, sh, 2, A);
        proj_kernel<32, 1><<<NTOK, 256, 64000, stream>>>(bufd, Wvl, bvl, nullptr, nullptr, 0, vb, nullptr);
        av_kernel<32><<<dim3(128, 2), 256, 0, stream>>>(vb, A, sh, 0, qb);   // o heads 0-1
        proj_kernel<32, 1><<<NTOK, 256, 64000, stream>>>(bufd, Wvl, bvl, nullptr, nullptr, 2, vb, nullptr);
        av_kernel<32><<<dim3(128, 2), 256, 0, stream>>>(vb, A, sh, 2, kb);   // o heads 2-3
        wo_mfma<32><<<NTOK, 256, 45056, stream>>>(qb, kb, Wol, bol, sh, bufd);
        mlp_fused<<<NTOK, 256, 45568, stream>>>(bufd, W1l, b1l, W2l, b2l);
    }

    out_mfma<<<NTOK, 256, 45056, stream>>>(bufd, h_oW1, f_ob1, f_oW2, f_ob2,
                                           d_out, flag);
}

// Round 9
// 2346.000 us; speedup vs baseline: 9.7349x; 1.0531x over previous
//
#include <hip/hip_runtime.h>
#include <math.h>

typedef unsigned short u16;
typedef unsigned int   u32;
typedef __attribute__((ext_vector_type(8))) short bf16x8;
typedef __attribute__((ext_vector_type(4))) float f32x4;

// ---------------- problem constants ----------------------------------------
// B=8, H=W=256, E=64, HID=128, SUB=16, WS=4, NH=4, dh=16, L=4
// tokens: 2048; residual d [tok][256 px][64 ch] fp32 (ch fastest)
// q/k/v/o slabs: [tok][256 px][32 ch] bf16 (one head-pair)
#define NTOK  2048
#define TOKSZ 16384ull

#define CBAR() __asm__ __volatile__("" ::: "memory")

__device__ __forceinline__ float bf2f(u16 b) { return __uint_as_float(((u32)b) << 16); }
__device__ __forceinline__ u16 f2bf(float f) {
    u32 u = __float_as_uint(f);
    u += 0x7FFFu + ((u >> 16) & 1u);
    return (u16)(u >> 16);
}
__device__ __forceinline__ float gelu_f(float x) {
    return 0.5f * x * (1.0f + erff(x * 0.70710678118654752440f));
}
__device__ __forceinline__ int shift_tok(int n) {
    int w = n >> 4, s = n & 15;
    int b = w >> 4, wy = (w >> 2) & 3, wx = w & 3;
    int ty = s >> 2, tx = s & 3;
    int gy = ((wy << 2) + ty + 2) & 15;
    int gx = ((wx << 2) + tx + 2) & 15;
    int w2 = (b << 4) + ((gy >> 2) << 2) + (gx >> 2);
    int s2 = ((gy & 3) << 2) + (gx & 3);
    return (w2 << 4) + s2;
}
// XOR-swizzled u16 tile index: row stride 64, chunk = 8 u16
__device__ __forceinline__ int swz(int row, int chunk) {
    return row * 64 + ((chunk ^ (row & 7)) << 3);
}

union U8 { uint4 u; bf16x8 b; };

// ---------------- dtype detection (proven) ---------------------------------
__global__ void detect_kernel(const u16* __restrict__ w1, int* __restrict__ flag) {
    int t = threadIdx.x, bad = 0;
    for (int i = t; i < 640; i += 64) {
        float ax = fabsf(bf2f(w1[i]));
        if (!(ax < 1e3f)) bad = 1;
    }
    unsigned long long m = __ballot(bad);
    if (t == 0) *flag = (m != 0ull) ? 1 : 0;
}

#define NWT 20
struct WArgs { const void* src[NWT]; int off16[NWT + 1]; int f32o[NWT]; };

__global__ __launch_bounds__(256)
void cvt_weights(WArgs a, const int* __restrict__ flag,
                 float* __restrict__ wbufA, u16* __restrict__ wbuf16) {
    int t = blockIdx.x * 256 + threadIdx.x;
    if (t >= a.off16[NWT]) return;
    int s = 0;
    while (a.off16[s + 1] <= t) ++s;
    int idx = t - a.off16[s];
    u16 raw; float v;
    if (*flag) { v = ((const float*)a.src[s])[idx]; raw = f2bf(v); }
    else       { raw = ((const u16*)a.src[s])[idx]; v = bf2f(raw); }
    wbuf16[t] = raw;
    if (a.f32o[s] >= 0) wbufA[a.f32o[s] + idx] = v;
}

// ---------------- embed: coords+3ch -> 128(gelu) -> 64, MFMA ---------------
__global__ __launch_bounds__(256, 3)
void embed_mfma(const void* __restrict__ vin, const int* __restrict__ flag,
                const float* __restrict__ W1, const float* __restrict__ b1,
                const u16* __restrict__ W2bf, const float* __restrict__ b2,
                const int* __restrict__ pdsy, const int* __restrict__ pdsx,
                float* __restrict__ d) {
    extern __shared__ char smem[];
    u16* hsT = (u16*)smem;             // [256][64] swizzled
    u16* wl  = (u16*)(smem + 32768);   // [64][64] swizzled
    int n = blockIdx.x, t = threadIdx.x;
    int wv = t >> 6, l = t & 63, m = l & 15, qd = l >> 4;
    int px0 = wv * 64;

    int w = n >> 4, s = n & 15;
    int b = w >> 4, wy = (w >> 2) & 3, wx = w & 3;
    int ty = s >> 2, tx = s & 3;
    int y = ((wy << 2) + ty) * 16 + (t >> 4);
    int x = ((wx << 2) + tx) * 16 + (t & 15);
    int fl = *flag;
    float in0 = ((float)y + 0.5f) * ((float)pdsy[0] * (1.0f / 256.0f));
    float in1 = ((float)x + 0.5f) * ((float)pdsx[0] * (1.0f / 256.0f));
    size_t pix = (size_t)b * 3 * 65536 + (size_t)y * 256 + (size_t)x;
    float in2 = fl ? ((const float*)vin)[pix]          : bf2f(((const u16*)vin)[pix]);
    float in3 = fl ? ((const float*)vin)[pix + 65536]  : bf2f(((const u16*)vin)[pix + 65536]);
    float in4 = fl ? ((const float*)vin)[pix + 131072] : bf2f(((const u16*)vin)[pix + 131072]);

    f32x4 acc[4][4];
    #pragma unroll
    for (int nt = 0; nt < 4; ++nt) {
        float bb = b2[nt * 16 + m];
        #pragma unroll
        for (int mt = 0; mt < 4; ++mt) acc[mt][nt] = {bb, bb, bb, bb};
    }
    for (int half = 0; half < 2; ++half) {
        if (half) __syncthreads();
        for (int h2 = 0; h2 < 64; h2 += 2) {
            int hid = half * 64 + h2;
            float ha = b1[hid] + W1[hid*5]*in0 + W1[hid*5+1]*in1 + W1[hid*5+2]*in2
                     + W1[hid*5+3]*in3 + W1[hid*5+4]*in4;
            float hb2 = b1[hid+1] + W1[hid*5+5]*in0 + W1[hid*5+6]*in1 + W1[hid*5+7]*in2
                     + W1[hid*5+8]*in3 + W1[hid*5+9]*in4;
            u32 pk = (u32)f2bf(gelu_f(ha)) | ((u32)f2bf(gelu_f(hb2)) << 16);
            *(u32*)&hsT[swz(t, h2 >> 3) + (h2 & 7)] = pk;
        }
        #pragma unroll
        for (int r = 0; r < 2; ++r) {
            int u = t + r * 256; int e = u >> 3, c8 = u & 7;
            *(uint4*)&wl[swz(e, c8)] = *(const uint4*)(W2bf + e * 128 + half * 64 + c8 * 8);
        }
        __syncthreads();
        #pragma unroll
        for (int ks = 0; ks < 2; ++ks) {
            U8 af[4], bf[4];
            #pragma unroll
            for (int mt = 0; mt < 4; ++mt)
                af[mt].u = *(const uint4*)&hsT[swz(px0 + mt*16 + m, ks*4 + qd)];
            #pragma unroll
            for (int nt = 0; nt < 4; ++nt)
                bf[nt].u = *(const uint4*)&wl[swz(nt*16 + m, ks*4 + qd)];
            #pragma unroll
            for (int mt = 0; mt < 4; ++mt)
                #pragma unroll
                for (int nt = 0; nt < 4; ++nt)
                    acc[mt][nt] = __builtin_amdgcn_mfma_f32_16x16x32_bf16(
                        af[mt].b, bf[nt].b, acc[mt][nt], 0, 0, 0);
        }
    }
    __syncthreads();
    float* eps = (float*)smem + wv * 2304;
    float* dp = d + (size_t)n * TOKSZ;
    #pragma unroll
    for (int ch2 = 0; ch2 < 2; ++ch2) {
        if (ch2) CBAR();
        #pragma unroll
        for (int mt = ch2*2; mt < ch2*2+2; ++mt)
            #pragma unroll
            for (int nt = 0; nt < 4; ++nt)
                #pragma unroll
                for (int r = 0; r < 4; ++r)
                    eps[((mt&1)*16 + qd*4 + r) * 68 + nt*16 + m] = acc[mt][nt][r];
        CBAR();
        #pragma unroll
        for (int j = 0; j < 8; ++j) {
            int f = l + 64*j; int row = f >> 4, c4 = f & 15;
            float4 v = *(float4*)&eps[row * 68 + c4 * 4];
            *(float4*)&dp[(px0 + ch2*32 + row) * 64 + c4 * 4] = v;
        }
    }
}

// ---------------- fused norm + projection (2 GEMMs, per-GEMM head base) ----
__global__ __launch_bounds__(256, 2)
void proj_kernel(const float* __restrict__ d,
                 const u16* __restrict__ Wa, const float* __restrict__ ba,
                 const u16* __restrict__ Wb, const float* __restrict__ bbp,
                 int ha, int hb,
                 u16* __restrict__ oa, u16* __restrict__ obp) {
    extern __shared__ char smem[];
    u16* xs = (u16*)smem;                      // [256][64] swizzled
    u16* wl = (u16*)(smem + 32768);            // [32][64] swizzled (8KB region)
    float* sarr = (float*)(smem + 32768);      // alias, stats phase
    float* murs = (float*)(smem + 40960);      // 512 B
    u16* ep = (u16*)(smem + 41472);            // 4 * 32*40 u16
    int n = blockIdx.x, t = threadIdx.x;
    const float4* gin = (const float4*)(d + (size_t)n * TOKSZ);
    int cb = (4 * t) & 63, g = t >> 4;
    float4 xv[16];
    float s0=0,s1=0,s2=0,s3=0,q0=0,q1=0,q2=0,q3=0;
    #pragma unroll
    for (int r = 0; r < 16; ++r) {
        float4 v = gin[t + r * 256]; xv[r] = v;
        s0 += v.x; q0 = fmaf(v.x, v.x, q0);
        s1 += v.y; q1 = fmaf(v.y, v.y, q1);
        s2 += v.z; q2 = fmaf(v.z, v.z, q2);
        s3 += v.w; q3 = fmaf(v.w, v.w, q3);
    }
    sarr[(cb+0)*16+g]=s0; sarr[(cb+1)*16+g]=s1; sarr[(cb+2)*16+g]=s2; sarr[(cb+3)*16+g]=s3;
    float* qarr = sarr + 1024;
    qarr[(cb+0)*16+g]=q0; qarr[(cb+1)*16+g]=q1; qarr[(cb+2)*16+g]=q2; qarr[(cb+3)*16+g]=q3;
    __syncthreads();
    if (t < 64) {
        float ss = 0.f, qq = 0.f;
        #pragma unroll
        for (int gg = 0; gg < 16; ++gg) { ss += sarr[t*16+gg]; qq += qarr[t*16+gg]; }
        float mu = ss * (1.0f/256.0f);
        float var = qq * (1.0f/256.0f) - mu * mu;
        murs[t] = mu; murs[64 + t] = rsqrtf(var + 1e-5f);
    }
    __syncthreads();
    {
        float m0 = murs[cb], m1 = murs[cb+1], m2 = murs[cb+2], m3 = murs[cb+3];
        float r0 = murs[64+cb], r1 = murs[64+cb+1], r2 = murs[64+cb+2], r3 = murs[64+cb+3];
        int c4 = t & 15;
        #pragma unroll
        for (int r = 0; r < 16; ++r) {
            float4 v = xv[r];
            int px = (t >> 4) + r * 16;
            uint2 o;
            o.x = (u32)f2bf((v.x-m0)*r0) | ((u32)f2bf((v.y-m1)*r1) << 16);
            o.y = (u32)f2bf((v.z-m2)*r2) | ((u32)f2bf((v.w-m3)*r3) << 16);
            *(uint2*)&xs[swz(px, c4 >> 1) + (c4 & 1) * 4] = o;
        }
    }
    int wv = t >> 6, l = t & 63, m = l & 15, qd = l >> 4;
    int px0 = wv * 64;
    const u16* Ws[2] = {Wa, Wb};
    const float* bs[2] = {ba, bbp};
    u16* outs[2] = {oa, obp};
    int hs[2] = {ha, hb};
    for (int ti = 0; ti < 2; ++ti) {
        if (ti) __syncthreads();
        for (int u = t; u < 256; u += 256) {
            int e = u >> 3, c8 = u & 7;
            *(uint4*)&wl[swz(e, c8)] =
                *(const uint4*)(Ws[ti] + (size_t)(hs[ti] * 16 + e) * 64 + c8 * 8);
        }
        __syncthreads();
        f32x4 acc[4][2];
        #pragma unroll
        for (int nt = 0; nt < 2; ++nt) {
            float bb = bs[ti][hs[ti] * 16 + nt * 16 + m];
            #pragma unroll
            for (int mt = 0; mt < 4; ++mt) acc[mt][nt] = {bb, bb, bb, bb};
        }
        #pragma unroll
        for (int ks = 0; ks < 2; ++ks) {
            U8 af[4], bf[2];
            #pragma unroll
            for (int mt = 0; mt < 4; ++mt)
                af[mt].u = *(const uint4*)&xs[swz(px0 + mt*16 + m, ks*4 + qd)];
            #pragma unroll
            for (int nt = 0; nt < 2; ++nt)
                bf[nt].u = *(const uint4*)&wl[swz(nt*16 + m, ks*4 + qd)];
            #pragma unroll
            for (int mt = 0; mt < 4; ++mt)
                #pragma unroll
                for (int nt = 0; nt < 2; ++nt)
                    acc[mt][nt] = __builtin_amdgcn_mfma_f32_16x16x32_bf16(
                        af[mt].b, bf[nt].b, acc[mt][nt], 0, 0, 0);
        }
        u16* epw = ep + wv * 1280;             // 32*(32+8)
        u16* dst0 = outs[ti] + (size_t)n * 8192;
        #pragma unroll
        for (int ch2 = 0; ch2 < 2; ++ch2) {
            if (ch2) CBAR();
            #pragma unroll
            for (int mt = ch2*2; mt < ch2*2+2; ++mt)
                #pragma unroll
                for (int nt = 0; nt < 2; ++nt)
                    #pragma unroll
                    for (int r = 0; r < 4; ++r)
                        epw[((mt&1)*16 + qd*4 + r) * 40 + nt*16 + m] = f2bf(acc[mt][nt][r]);
            CBAR();
            #pragma unroll
            for (int u = l; u < 128; u += 64) {
                int row = u >> 2, c8 = u & 3;
                *(uint4*)(dst0 + (size_t)(px0 + ch2*32 + row) * 32 + c8*8)
                    = *(uint4*)&epw[row * 40 + c8*8];
            }
        }
    }
}

// ---------------- scores via MFMA + softmax (CW=32 slabs) ------------------
__global__ __launch_bounds__(256, 4)
void scores_mfma(const u16* __restrict__ q, const u16* __restrict__ k,
                 int shifted, int hbase, float* __restrict__ A) {
    int w = blockIdx.x, hy = blockIdx.y, t = threadIdx.x;
    int wv = t >> 6, l = t & 63, m = l & 15, qd = l >> 4;
    int n0 = w * 16 + m;
    int ni = shifted ? shift_tok(n0) : n0;
    size_t base = (size_t)ni * 8192 + hy * 16 + (qd & 1) * 8;
    const u16* qrow = q + base;
    const u16* krow = k + base;
    int pxb = wv * 64 + (qd >> 1);
    f32x4 acc = {0.f, 0.f, 0.f, 0.f};
    for (int s = 0; s < 32; ++s) {
        U8 qa, kv;
        qa.u = *(const uint4*)(qrow + (size_t)(pxb + s*2) * 32);
        kv.u = *(const uint4*)(krow + (size_t)(pxb + s*2) * 32);
        acc = __builtin_amdgcn_mfma_f32_16x16x32_bf16(qa.b, kv.b, acc, 0, 0, 0);
    }
    __shared__ float pc[4][256];
    #pragma unroll
    for (int r = 0; r < 4; ++r) pc[wv][l * 4 + r] = acc[r];
    __syncthreads();
    if (wv == 0) {
        float* arow = A + ((size_t)(w * 4 + hbase + hy) * 16) * 16;
        #pragma unroll
        for (int r = 0; r < 4; ++r) {
            float sc = (pc[0][l*4+r] + pc[1][l*4+r] + pc[2][l*4+r] + pc[3][l*4+r])
                     * (1.0f / 1024.0f);
            float mx = sc;
            #pragma unroll
            for (int off = 1; off < 16; off <<= 1) mx = fmaxf(mx, __shfl_xor(mx, off, 16));
            float e = expf(sc - mx);
            float ssum = e;
            #pragma unroll
            for (int off = 1; off < 16; off <<= 1) ssum += __shfl_xor(ssum, off, 16);
            arow[(qd * 4 + r) * 16 + m] = e / ssum;
        }
    }
}

// ---------------- o = A @ v (full-line IO, both heads per block) -----------
__global__ __launch_bounds__(256, 4)
void av_kernel(const u16* __restrict__ v, const float* __restrict__ A,
               int shifted, int hbase, u16* __restrict__ o) {
    int w = blockIdx.x, t = threadIdx.x;
    __shared__ int nis[16];
    __shared__ float As[512];
    if (t < 16) { int n = w * 16 + t; nis[t] = shifted ? shift_tok(n) : n; }
    As[t]       = A[(size_t)(w * 4 + hbase)     * 256 + t];
    As[256 + t] = A[(size_t)(w * 4 + hbase + 1) * 256 + t];
    __syncthreads();
    for (int it = 0; it < 4; ++it) {
        int idx = (blockIdx.y * 4 + it) * 256 + t;
        int px = idx >> 4, cpair = idx & 15, hy = cpair >> 3;
        int off = px * 32 + cpair * 2;
        const float* Ah = As + hy * 256;
        float v0[16], v1[16];
        #pragma unroll
        for (int j = 0; j < 16; ++j) {
            u32 pv = *(const u32*)(v + (size_t)nis[j] * 8192 + off);
            v0[j] = __uint_as_float(pv << 16);
            v1[j] = __uint_as_float(pv & 0xFFFF0000u);
        }
        #pragma unroll
        for (int i = 0; i < 16; ++i) {
            float a0 = 0.f, a1 = 0.f;
            #pragma unroll
            for (int j = 0; j < 16; ++j) {
                float aw = Ah[i * 16 + j];
                a0 = fmaf(aw, v0[j], a0);
                a1 = fmaf(aw, v1[j], a1);
            }
            *(u32*)(o + (size_t)(w * 16 + i) * 8192 + off)
                = (u32)f2bf(a0) | ((u32)f2bf(a1) << 16);
        }
    }
}

// ---------------- Wo MFMA (K=64 from 2 slabs) + residual RMW ---------------
__global__ __launch_bounds__(256, 3)
void wo_mfma(const u16* __restrict__ o1, const u16* __restrict__ o2,
             const u16* __restrict__ Wo, const float* __restrict__ bo,
             int shifted, float* __restrict__ dres) {
    extern __shared__ char smem[];
    u16* xs = (u16*)smem;              // [256][64] swizzled
    u16* wl = (u16*)(smem + 32768);    // [64][64] swizzled
    int n = blockIdx.x, t = threadIdx.x;
    int wv = t >> 6, l = t & 63, m = l & 15, qd = l >> 4;
    int px0 = wv * 64;
    int no = shifted ? shift_tok(n) : n;
    #pragma unroll
    for (int r = 0; r < 8; ++r) {
        int u = t + r * 256;
        int px = u >> 3, c8 = u & 7;
        const u16* src = (c8 < 4) ? (o1 + (size_t)n * 8192 + px * 32 + c8 * 8)
                                  : (o2 + (size_t)n * 8192 + px * 32 + (c8 - 4) * 8);
        *(uint4*)&xs[swz(px, c8)] = *(const uint4*)src;
    }
    #pragma unroll
    for (int r = 0; r < 2; ++r) {
        int u = t + r * 256;
        int e = u >> 3, c8 = u & 7;
        *(uint4*)&wl[swz(e, c8)] = *(const uint4*)(Wo + e * 64 + c8 * 8);
    }
    __syncthreads();
    f32x4 acc[4][4];
    #pragma unroll
    for (int nt = 0; nt < 4; ++nt) {
        float bb = bo[nt * 16 + m];
        #pragma unroll
        for (int mt = 0; mt < 4; ++mt) acc[mt][nt] = {bb, bb, bb, bb};
    }
    #pragma unroll
    for (int ks = 0; ks < 2; ++ks) {
        U8 af[4], bf[4];
        #pragma unroll
        for (int mt = 0; mt < 4; ++mt)
            af[mt].u = *(const uint4*)&xs[swz(px0 + mt*16 + m, ks*4 + qd)];
        #pragma unroll
        for (int nt = 0; nt < 4; ++nt)
            bf[nt].u = *(const uint4*)&wl[swz(nt*16 + m, ks*4 + qd)];
        #pragma unroll
        for (int mt = 0; mt < 4; ++mt)
            #pragma unroll
            for (int nt = 0; nt < 4; ++nt)
                acc[mt][nt] = __builtin_amdgcn_mfma_f32_16x16x32_bf16(
                    af[mt].b, bf[nt].b, acc[mt][nt], 0, 0, 0);
    }
    __syncthreads();
    float* eps = (float*)smem + wv * 2304;
    float* dp = dres + (size_t)no * TOKSZ;
    #pragma unroll
    for (int ch2 = 0; ch2 < 2; ++ch2) {
        if (ch2) CBAR();
        #pragma unroll
        for (int mt = ch2*2; mt < ch2*2+2; ++mt)
            #pragma unroll
            for (int nt = 0; nt < 4; ++nt)
                #pragma unroll
                for (int r = 0; r < 4; ++r)
                    eps[((mt&1)*16 + qd*4 + r) * 68 + nt*16 + m] = acc[mt][nt][r];
        CBAR();
        #pragma unroll
        for (int j = 0; j < 8; ++j) {
            int f = l + 64*j; int row = f >> 4, c4 = f & 15;
            float4 dv = *(float4*)&eps[row * 68 + c4 * 4];
            float* gp = &dp[(px0 + ch2*32 + row) * 64 + c4 * 4];
            float4 gv = *(float4*)gp;
            gv.x += dv.x; gv.y += dv.y; gv.z += dv.z; gv.w += dv.w;
            *(float4*)gp = gv;
        }
    }
}

// ---------------- fused norm + MLP + register-residual ---------------------
__global__ __launch_bounds__(256, 2)
void mlp_fused(float* __restrict__ dres,
               const u16* __restrict__ W1, const float* __restrict__ b1,
               const u16* __restrict__ W2, const float* __restrict__ b2) {
    extern __shared__ char smem[];
    u16* xs = (u16*)smem;                      // [256][64] swizzled; xhat then h
    u16* wl = (u16*)(smem + 32768);
    float* sarr = (float*)(smem + 32768);
    float* murs = (float*)(smem + 40960);
    int n = blockIdx.x, t = threadIdx.x;
    int wv = t >> 6, l = t & 63, m = l & 15, qd = l >> 4;
    int px0 = wv * 64;
    int rbase = l >> 4, c4 = l & 15;
    const float4* gin = (const float4*)(dres + (size_t)n * TOKSZ);
    float4 xv[2][8];
    float s0=0,s1=0,s2=0,s3=0,q0=0,q1=0,q2=0,q3=0;
    #pragma unroll
    for (int ch2 = 0; ch2 < 2; ++ch2)
        #pragma unroll
        for (int j = 0; j < 8; ++j) {
            float4 v = gin[(px0 + ch2*32 + rbase + 4*j) * 16 + c4];
            xv[ch2][j] = v;
            s0 += v.x; q0 = fmaf(v.x, v.x, q0);
            s1 += v.y; q1 = fmaf(v.y, v.y, q1);
            s2 += v.z; q2 = fmaf(v.z, v.z, q2);
            s3 += v.w; q3 = fmaf(v.w, v.w, q3);
        }
    int cb = 4 * c4, g = t >> 4;
    sarr[(cb+0)*16+g]=s0; sarr[(cb+1)*16+g]=s1; sarr[(cb+2)*16+g]=s2; sarr[(cb+3)*16+g]=s3;
    float* qarr = sarr + 1024;
    qarr[(cb+0)*16+g]=q0; qarr[(cb+1)*16+g]=q1; qarr[(cb+2)*16+g]=q2; qarr[(cb+3)*16+g]=q3;
    __syncthreads();
    if (t < 64) {
        float ss = 0.f, qq = 0.f;
        #pragma unroll
        for (int gg = 0; gg < 16; ++gg) { ss += sarr[t*16+gg]; qq += qarr[t*16+gg]; }
        float mu = ss * (1.0f/256.0f);
        float var = qq * (1.0f/256.0f) - mu * mu;
        murs[t] = mu; murs[64 + t] = rsqrtf(var + 1e-5f);
    }
    __syncthreads();
    {
        float m0 = murs[cb], m1 = murs[cb+1], m2 = murs[cb+2], m3 = murs[cb+3];
        float r0 = murs[64+cb], r1 = murs[64+cb+1], r2 = murs[64+cb+2], r3 = murs[64+cb+3];
        #pragma unroll
        for (int ch2 = 0; ch2 < 2; ++ch2)
            #pragma unroll
            for (int j = 0; j < 8; ++j) {
                float4 v = xv[ch2][j];
                int row = px0 + ch2*32 + rbase + 4*j;
                uint2 o;
                o.x = (u32)f2bf((v.x-m0)*r0) | ((u32)f2bf((v.y-m1)*r1) << 16);
                o.y = (u32)f2bf((v.z-m2)*r2) | ((u32)f2bf((v.w-m3)*r3) << 16);
                *(uint2*)&xs[swz(row, c4 >> 1) + (c4 & 1) * 4] = o;
            }
    }
    #pragma unroll
    for (int r = 0; r < 2; ++r) {
        int u = t + r * 256;
        int e = u >> 3, c8 = u & 7;
        *(uint4*)&wl[swz(e, c8)] = *(const uint4*)(W1 + e * 64 + c8 * 8);
    }
    __syncthreads();
    f32x4 acc[4][4];
    #pragma unroll
    for (int nt = 0; nt < 4; ++nt) {
        float bb = b1[nt * 16 + m];
        #pragma unroll
        for (int mt = 0; mt < 4; ++mt) acc[mt][nt] = {bb, bb, bb, bb};
    }
    #pragma unroll
    for (int ks = 0; ks < 2; ++ks) {
        U8 af[4], bf[4];
        #pragma unroll
        for (int mt = 0; mt < 4; ++mt)
            af[mt].u = *(const uint4*)&xs[swz(px0 + mt*16 + m, ks*4 + qd)];
        #pragma unroll
        for (int nt = 0; nt < 4; ++nt)
            bf[nt].u = *(const uint4*)&wl[swz(nt*16 + m, ks*4 + qd)];
        #pragma unroll
        for (int mt = 0; mt < 4; ++mt)
            #pragma unroll
            for (int nt = 0; nt < 4; ++nt)
                acc[mt][nt] = __builtin_amdgcn_mfma_f32_16x16x32_bf16(
                    af[mt].b, bf[nt].b, acc[mt][nt], 0, 0, 0);
    }
    __syncthreads();
    #pragma unroll
    for (int nt = 0; nt < 4; ++nt) {
        int ch = nt * 16 + m;
        #pragma unroll
        for (int mt = 0; mt < 4; ++mt)
            #pragma unroll
            for (int r = 0; r < 4; ++r) {
                int R = px0 + mt*16 + qd*4 + r;
                xs[swz(R, ch >> 3) + (ch & 7)] = f2bf(gelu_f(acc[mt][nt][r]));
            }
    }
    #pragma unroll
    for (int r = 0; r < 2; ++r) {
        int u = t + r * 256;
        int e = u >> 3, c8 = u & 7;
        *(uint4*)&wl[swz(e, c8)] = *(const uint4*)(W2 + e * 64 + c8 * 8);
    }
    __syncthreads();
    #pragma unroll
    for (int nt = 0; nt < 4; ++nt) {
        float bb = b2[nt * 16 + m];
        #pragma unroll
        for (int mt = 0; mt < 4; ++mt) acc[mt][nt] = {bb, bb, bb, bb};
    }
    #pragma unroll
    for (int ks = 0; ks < 2; ++ks) {
        U8 af[4], bf[4];
        #pragma unroll
        for (int mt = 0; mt < 4; ++mt)
            af[mt].u = *(const uint4*)&xs[swz(px0 + mt*16 + m, ks*4 + qd)];
        #pragma unroll
        for (int nt = 0; nt < 4; ++nt)
            bf[nt].u = *(const uint4*)&wl[swz(nt*16 + m, ks*4 + qd)];
        #pragma unroll
        for (int mt = 0; mt < 4; ++mt)
            #pragma unroll
            for (int nt = 0; nt < 4; ++nt)
                acc[mt][nt] = __builtin_amdgcn_mfma_f32_16x16x32_bf16(
                    af[mt].b, bf[nt].b, acc[mt][nt], 0, 0, 0);
    }
    __syncthreads();
    float* eps = (float*)smem + wv * 2304;
    float* dp = dres + (size_t)n * TOKSZ;
    #pragma unroll
    for (int ch2 = 0; ch2 < 2; ++ch2) {
        if (ch2) CBAR();
        #pragma unroll
        for (int mt = ch2*2; mt < ch2*2+2; ++mt)
            #pragma unroll
            for (int nt = 0; nt < 4; ++nt)
                #pragma unroll
                for (int r = 0; r < 4; ++r)
                    eps[((mt&1)*16 + qd*4 + r) * 68 + nt*16 + m] = acc[mt][nt][r];
        CBAR();
        #pragma unroll
        for (int j = 0; j < 8; ++j) {
            int f = l + 64*j; int row = f >> 4, cc = f & 15;
            float4 dv = *(float4*)&eps[row * 68 + cc * 4];
            float4 bs = xv[ch2][j];                   // residual from registers
            bs.x += dv.x; bs.y += dv.y; bs.z += dv.z; bs.w += dv.w;
            *(float4*)&dp[(px0 + ch2*32 + row) * 64 + cc * 4] = bs;
        }
    }
}

// ---------------- output MLP via MFMA: 64 -> 128(gelu) -> 1 ----------------
__global__ __launch_bounds__(256, 3)
void out_mfma(const float* __restrict__ d,
              const u16* __restrict__ W1, const float* __restrict__ b1,
              const float* __restrict__ W2, const float* __restrict__ b2,
              void* __restrict__ out, const int* __restrict__ flag) {
    extern __shared__ char smem[];
    u16* xs = (u16*)smem;
    u16* wl = (u16*)(smem + 32768);
    int n = blockIdx.x, t = threadIdx.x;
    int wv = t >> 6, l = t & 63, m = l & 15, qd = l >> 4;
    int px0 = wv * 64;
    const float4* gin = (const float4*)(d + (size_t)n * TOKSZ);
    #pragma unroll
    for (int r = 0; r < 16; ++r) {
        float4 xv = gin[t + r * 256];
        int fi = t + r * 256;
        int px = fi >> 4, c4 = fi & 15;
        uint2 o;
        o.x = (u32)f2bf(xv.x) | ((u32)f2bf(xv.y) << 16);
        o.y = (u32)f2bf(xv.z) | ((u32)f2bf(xv.w) << 16);
        *(uint2*)&xs[swz(px, c4 >> 1) + (c4 & 1) * 4] = o;
    }
    float val[4][4];
    #pragma unroll
    for (int mt = 0; mt < 4; ++mt)
        #pragma unroll
        for (int r = 0; r < 4; ++r) val[mt][r] = 0.f;
    for (int nh = 0; nh < 2; ++nh) {
        if (nh) __syncthreads();
        #pragma unroll
        for (int r = 0; r < 2; ++r) {
            int u = t + r * 256;
            int e = u >> 3, c8 = u & 7;
            *(uint4*)&wl[swz(e, c8)] = *(const uint4*)(W1 + (size_t)nh * 4096 + e * 64 + c8 * 8);
        }
        __syncthreads();
        f32x4 acc[4][4];
        #pragma unroll
        for (int nt = 0; nt < 4; ++nt) {
            float bb = b1[nh * 64 + nt * 16 + m];
            #pragma unroll
            for (int mt = 0; mt < 4; ++mt) acc[mt][nt] = {bb, bb, bb, bb};
        }
        #pragma unroll
        for (int ks = 0; ks < 2; ++ks) {
            U8 af[4], bf[4];
            #pragma unroll
            for (int mt = 0; mt < 4; ++mt)
                af[mt].u = *(const uint4*)&xs[swz(px0 + mt*16 + m, ks*4 + qd)];
            #pragma unroll
            for (int nt = 0; nt < 4; ++nt)
                bf[nt].u = *(const uint4*)&wl[swz(nt*16 + m, ks*4 + qd)];
            #pragma unroll
            for (int mt = 0; mt < 4; ++mt)
                #pragma unroll
                for (int nt = 0; nt < 4; ++nt)
                    acc[mt][nt] = __builtin_amdgcn_mfma_f32_16x16x32_bf16(
                        af[mt].b, bf[nt].b, acc[mt][nt], 0, 0, 0);
        }
        float w2v[4];
        #pragma unroll
        for (int nt = 0; nt < 4; ++nt) w2v[nt] = W2[nh * 64 + nt * 16 + m];
        #pragma unroll
        for (int mt = 0; mt < 4; ++mt)
            #pragma unroll
            for (int r = 0; r < 4; ++r) {
                float p = 0.f;
                #pragma unroll
                for (int nt = 0; nt < 4; ++nt)
                    p = fmaf(gelu_f(acc[mt][nt][r]), w2v[nt], p);
                val[mt][r] += p;
            }
    }
    __syncthreads();
    float* red = (float*)smem;                 // [256][17]
    #pragma unroll
    for (int mt = 0; mt < 4; ++mt)
        #pragma unroll
        for (int r = 0; r < 4; ++r)
            red[(px0 + mt*16 + qd*4 + r) * 17 + m] = val[mt][r];
    __syncthreads();
    float a = b2[0];
    #pragma unroll
    for (int j = 0; j < 16; ++j) a += red[t * 17 + j];
    int w = n >> 4, s = n & 15;
    int b = w >> 4, wy = (w >> 2) & 3, wx = w & 3;
    int ty = s >> 2, tx = s & 3;
    int y = ((wy << 2) + ty) * 16 + (t >> 4);
    int x = ((wx << 2) + tx) * 16 + (t & 15);
    size_t oi = (size_t)b * 65536 + (size_t)y * 256 + (size_t)x;
    if (*flag) ((float*)out)[oi] = a;
    else       ((u16*)out)[oi] = f2bf(a);
}

// ---------------- host launch ----------------------------------------------
extern "C" void kernel_launch(void* const* d_in, const int* in_sizes, int n_in,
                              void* d_out, int out_size, void* d_ws, size_t ws_size,
                              hipStream_t stream) {
    (void)n_in; (void)out_size; (void)ws_size;
    const int* pdsy = (const int*)d_in[21];
    const int* pdsx = (const int*)d_in[22];

    // proven 235.65 MB layout (R8)
    char* wsb = (char*)d_ws;
    float* bufd = (float*)wsb;
    u16* qb = (u16*)(wsb + 134217728ull);
    u16* kb = (u16*)(wsb + 167772160ull);
    u16* vb = (u16*)(wsb + 201326592ull);
    float* A     = (float*)(wsb + 234881024ull);
    float* wbufA = (float*)(wsb + 235405312ull);
    u16* wbuf16  = (u16*)(wsb + 235416064ull);
    int* flag    = (int*)(wsb + 235650816ull);

    const int f32set[12] = {1, 2, 4, 6, 8, 10, 12, 14, 16, 18, 19, 20};
    WArgs wa;
    int off16[NWT + 1]; off16[0] = 0;
    int c32[NWT + 1];
    int fo = 0;
    for (int i = 0; i < NWT; ++i) {
        int di = i + 1;
        wa.src[i] = d_in[di];
        off16[i + 1] = off16[i] + in_sizes[di];
        wa.off16[i] = off16[i];
        int isf = 0;
        for (int j = 0; j < 12; ++j) if (f32set[j] == di) isf = 1;
        wa.f32o[i] = isf ? fo : -1;
        c32[di] = isf ? fo : -1;
        if (isf) fo += in_sizes[di];
    }
    wa.off16[NWT] = off16[NWT];

    detect_kernel<<<1, 64, 0, stream>>>((const u16*)d_in[1], flag);
    cvt_weights<<<(off16[NWT] + 255) / 256, 256, 0, stream>>>(wa, flag, wbufA, wbuf16);

    const float* f_inpW1 = wbufA + c32[1];
    const float* f_inpb1 = wbufA + c32[2];
    const float* f_inpb2 = wbufA + c32[4];
    const float* f_bq  = wbufA + c32[6];
    const float* f_bk  = wbufA + c32[8];
    const float* f_bv  = wbufA + c32[10];
    const float* f_bo  = wbufA + c32[12];
    const float* f_mb1 = wbufA + c32[14];
    const float* f_mb2 = wbufA + c32[16];
    const float* f_ob1 = wbufA + c32[18];
    const float* f_oW2 = wbufA + c32[19];
    const float* f_ob2 = wbufA + c32[20];
    const u16* h_inpW2 = wbuf16 + off16[2];
    const u16* h_Wq  = wbuf16 + off16[4];
    const u16* h_Wk  = wbuf16 + off16[6];
    const u16* h_Wv  = wbuf16 + off16[8];
    const u16* h_Wo  = wbuf16 + off16[10];
    const u16* h_mW1 = wbuf16 + off16[12];
    const u16* h_mW2 = wbuf16 + off16[14];
    const u16* h_oW1 = wbuf16 + off16[16];

    embed_mfma<<<NTOK, 256, 40960, stream>>>(d_in[0], flag, f_inpW1, f_inpb1,
                                             h_inpW2, f_inpb2, pdsy, pdsx, bufd);

    for (int l = 0; l < 4; ++l) {
        int sh = l & 1;
        const u16* Wql = h_Wq + l * 4096;  const float* bql = f_bq + l * 64;
        const u16* Wkl = h_Wk + l * 4096;  const float* bkl = f_bk + l * 64;
        const u16* Wvl = h_Wv + l * 4096;  const float* bvl = f_bv + l * 64;
        const u16* Wol = h_Wo + l * 4096;  const float* bol = f_bo + l * 64;
        const u16* W1l = h_mW1 + l * 4096; const float* b1l = f_mb1 + l * 64;
        const u16* W2l = h_mW2 + l * 4096; const float* b2l = f_mb2 + l * 64;

        proj_kernel<<<NTOK, 256, 51712, stream>>>(bufd, Wql, bql, Wkl, bkl, 0, 0, qb, kb);
        scores_mfma<<<dim3(128, 2), 256, 0, stream>>>(qb, kb, sh, 0, A);
        proj_kernel<<<NTOK, 256, 51712, stream>>>(bufd, Wql, bql, Wkl, bkl, 2, 2, qb, kb);
        scores_mfma<<<dim3(128, 2), 256, 0, stream>>>(qb, kb, sh, 2, A);
        proj_kernel<<<NTOK, 256, 51712, stream>>>(bufd, Wvl, bvl, Wvl, bvl, 0, 2, vb, qb);
        av_kernel<<<dim3(128, 4), 256, 0, stream>>>(vb, A, sh, 0, kb);   // o heads 0-1
        av_kernel<<<dim3(128, 4), 256, 0, stream>>>(qb, A, sh, 2, vb);   // o heads 2-3
        wo_mfma<<<NTOK, 256, 40960, stream>>>(kb, vb, Wol, bol, sh, bufd);
        mlp_fused<<<NTOK, 256, 41472, stream>>>(bufd, W1l, b1l, W2l, b2l);
    }

    out_mfma<<<NTOK, 256, 40960, stream>>>(bufd, h_oW1, f_ob1, f_oW2, f_ob2,
                                           d_out, flag);
}

// Round 10
// 1495.660 us; speedup vs baseline: 15.2695x; 1.5685x over previous
//
#include <hip/hip_runtime.h>
#include <math.h>

typedef unsigned short u16;
typedef unsigned int   u32;
typedef __attribute__((ext_vector_type(8))) short bf16x8;
typedef __attribute__((ext_vector_type(4))) float f32x4;

// ---------------- problem constants ----------------------------------------
// B=8, H=W=256, E=64, HID=128, SUB=16, WS=4, NH=4, dh=16, L=4
// tokens: 2048; residual d [tok][256 px][64 ch] fp32 (ch fastest)
// q/k/v slabs: [tok][256 px][32 ch] bf16 (one head-pair)
#define NTOK  2048
#define TOKSZ 16384ull

#define CBAR() __asm__ __volatile__("" ::: "memory")

__device__ __forceinline__ float bf2f(u16 b) { return __uint_as_float(((u32)b) << 16); }
__device__ __forceinline__ u16 f2bf(float f) {
    u32 u = __float_as_uint(f);
    u += 0x7FFFu + ((u >> 16) & 1u);
    return (u16)(u >> 16);
}
__device__ __forceinline__ float gelu_f(float x) {
    return 0.5f * x * (1.0f + erff(x * 0.70710678118654752440f));
}
__device__ __forceinline__ int shift_tok(int n) {
    int w = n >> 4, s = n & 15;
    int b = w >> 4, wy = (w >> 2) & 3, wx = w & 3;
    int ty = s >> 2, tx = s & 3;
    int gy = ((wy << 2) + ty + 2) & 15;
    int gx = ((wx << 2) + tx + 2) & 15;
    int w2 = (b << 4) + ((gy >> 2) << 2) + (gx >> 2);
    int s2 = ((gy & 3) << 2) + (gx & 3);
    return (w2 << 4) + s2;
}
// XOR-swizzled u16 tile index: row stride 64, chunk = 8 u16
__device__ __forceinline__ int swz(int row, int chunk) {
    return row * 64 + ((chunk ^ (row & 7)) << 3);
}

union U8 { uint4 u; bf16x8 b; };

// ---------------- dtype detection (proven) ---------------------------------
__global__ void detect_kernel(const u16* __restrict__ w1, int* __restrict__ flag) {
    int t = threadIdx.x, bad = 0;
    for (int i = t; i < 640; i += 64) {
        float ax = fabsf(bf2f(w1[i]));
        if (!(ax < 1e3f)) bad = 1;
    }
    unsigned long long m = __ballot(bad);
    if (t == 0) *flag = (m != 0ull) ? 1 : 0;
}

#define NWT 20
struct WArgs { const void* src[NWT]; int off16[NWT + 1]; int f32o[NWT]; };

__global__ __launch_bounds__(256)
void cvt_weights(WArgs a, const int* __restrict__ flag,
                 float* __restrict__ wbufA, u16* __restrict__ wbuf16) {
    int t = blockIdx.x * 256 + threadIdx.x;
    if (t >= a.off16[NWT]) return;
    int s = 0;
    while (a.off16[s + 1] <= t) ++s;
    int idx = t - a.off16[s];
    u16 raw; float v;
    if (*flag) { v = ((const float*)a.src[s])[idx]; raw = f2bf(v); }
    else       { raw = ((const u16*)a.src[s])[idx]; v = bf2f(raw); }
    wbuf16[t] = raw;
    if (a.f32o[s] >= 0) wbufA[a.f32o[s] + idx] = v;
}

// ---------------- embed: coords+3ch -> 128(gelu) -> 64, MFMA ---------------
__global__ __launch_bounds__(256, 3)
void embed_mfma(const void* __restrict__ vin, const int* __restrict__ flag,
                const float* __restrict__ W1, const float* __restrict__ b1,
                const u16* __restrict__ W2bf, const float* __restrict__ b2,
                const int* __restrict__ pdsy, const int* __restrict__ pdsx,
                float* __restrict__ d) {
    extern __shared__ char smem[];
    u16* hsT = (u16*)smem;             // [256][64] swizzled
    u16* wl  = (u16*)(smem + 32768);   // [64][64] swizzled
    int n = blockIdx.x, t = threadIdx.x;
    int wv = t >> 6, l = t & 63, m = l & 15, qd = l >> 4;
    int px0 = wv * 64;

    int w = n >> 4, s = n & 15;
    int b = w >> 4, wy = (w >> 2) & 3, wx = w & 3;
    int ty = s >> 2, tx = s & 3;
    int y = ((wy << 2) + ty) * 16 + (t >> 4);
    int x = ((wx << 2) + tx) * 16 + (t & 15);
    int fl = *flag;
    float in0 = ((float)y + 0.5f) * ((float)pdsy[0] * (1.0f / 256.0f));
    float in1 = ((float)x + 0.5f) * ((float)pdsx[0] * (1.0f / 256.0f));
    size_t pix = (size_t)b * 3 * 65536 + (size_t)y * 256 + (size_t)x;
    float in2 = fl ? ((const float*)vin)[pix]          : bf2f(((const u16*)vin)[pix]);
    float in3 = fl ? ((const float*)vin)[pix + 65536]  : bf2f(((const u16*)vin)[pix + 65536]);
    float in4 = fl ? ((const float*)vin)[pix + 131072] : bf2f(((const u16*)vin)[pix + 131072]);

    f32x4 acc[4][4];
    #pragma unroll
    for (int nt = 0; nt < 4; ++nt) {
        float bb = b2[nt * 16 + m];
        #pragma unroll
        for (int mt = 0; mt < 4; ++mt) acc[mt][nt] = {bb, bb, bb, bb};
    }
    for (int half = 0; half < 2; ++half) {
        if (half) __syncthreads();
        for (int h2 = 0; h2 < 64; h2 += 2) {
            int hid = half * 64 + h2;
            float ha = b1[hid] + W1[hid*5]*in0 + W1[hid*5+1]*in1 + W1[hid*5+2]*in2
                     + W1[hid*5+3]*in3 + W1[hid*5+4]*in4;
            float hb2 = b1[hid+1] + W1[hid*5+5]*in0 + W1[hid*5+6]*in1 + W1[hid*5+7]*in2
                     + W1[hid*5+8]*in3 + W1[hid*5+9]*in4;
            u32 pk = (u32)f2bf(gelu_f(ha)) | ((u32)f2bf(gelu_f(hb2)) << 16);
            *(u32*)&hsT[swz(t, h2 >> 3) + (h2 & 7)] = pk;
        }
        #pragma unroll
        for (int r = 0; r < 2; ++r) {
            int u = t + r * 256; int e = u >> 3, c8 = u & 7;
            *(uint4*)&wl[swz(e, c8)] = *(const uint4*)(W2bf + e * 128 + half * 64 + c8 * 8);
        }
        __syncthreads();
        #pragma unroll
        for (int ks = 0; ks < 2; ++ks) {
            U8 af[4], bf[4];
            #pragma unroll
            for (int mt = 0; mt < 4; ++mt)
                af[mt].u = *(const uint4*)&hsT[swz(px0 + mt*16 + m, ks*4 + qd)];
            #pragma unroll
            for (int nt = 0; nt < 4; ++nt)
                bf[nt].u = *(const uint4*)&wl[swz(nt*16 + m, ks*4 + qd)];
            #pragma unroll
            for (int mt = 0; mt < 4; ++mt)
                #pragma unroll
                for (int nt = 0; nt < 4; ++nt)
                    acc[mt][nt] = __builtin_amdgcn_mfma_f32_16x16x32_bf16(
                        af[mt].b, bf[nt].b, acc[mt][nt], 0, 0, 0);
        }
    }
    __syncthreads();
    float* eps = (float*)smem + wv * 2304;
    float* dp = d + (size_t)n * TOKSZ;
    #pragma unroll
    for (int ch2 = 0; ch2 < 2; ++ch2) {
        if (ch2) CBAR();
        #pragma unroll
        for (int mt = ch2*2; mt < ch2*2+2; ++mt)
            #pragma unroll
            for (int nt = 0; nt < 4; ++nt)
                #pragma unroll
                for (int r = 0; r < 4; ++r)
                    eps[((mt&1)*16 + qd*4 + r) * 68 + nt*16 + m] = acc[mt][nt][r];
        CBAR();
        #pragma unroll
        for (int j = 0; j < 8; ++j) {
            int f = l + 64*j; int row = f >> 4, c4 = f & 15;
            float4 v = *(float4*)&eps[row * 68 + c4 * 4];
            *(float4*)&dp[(px0 + ch2*32 + row) * 64 + c4 * 4] = v;
        }
    }
}

// ---------------- fused norm + projection (2 GEMMs, per-GEMM head base) ----
__global__ __launch_bounds__(256, 3)
void proj_kernel(const float* __restrict__ d,
                 const u16* __restrict__ Wa, const float* __restrict__ ba,
                 const u16* __restrict__ Wb, const float* __restrict__ bbp,
                 int ha, int hb,
                 u16* __restrict__ oa, u16* __restrict__ obp) {
    extern __shared__ char smem[];
    u16* xs = (u16*)smem;                      // [256][64] swizzled
    u16* wl = (u16*)(smem + 32768);            // [32][64] region (aliases sarr)
    float* sarr = (float*)(smem + 32768);
    float* murs = (float*)(smem + 40960);      // 512 B
    u16* ep = (u16*)(smem + 41472);            // 4 * 32*40 u16
    int n = blockIdx.x, t = threadIdx.x;
    const float4* gin = (const float4*)(d + (size_t)n * TOKSZ);
    int cb = (4 * t) & 63, g = t >> 4;
    float4 xv[16];
    float s0=0,s1=0,s2=0,s3=0,q0=0,q1=0,q2=0,q3=0;
    #pragma unroll
    for (int r = 0; r < 16; ++r) {
        float4 v = gin[t + r * 256]; xv[r] = v;
        s0 += v.x; q0 = fmaf(v.x, v.x, q0);
        s1 += v.y; q1 = fmaf(v.y, v.y, q1);
        s2 += v.z; q2 = fmaf(v.z, v.z, q2);
        s3 += v.w; q3 = fmaf(v.w, v.w, q3);
    }
    sarr[(cb+0)*16+g]=s0; sarr[(cb+1)*16+g]=s1; sarr[(cb+2)*16+g]=s2; sarr[(cb+3)*16+g]=s3;
    float* qarr = sarr + 1024;
    qarr[(cb+0)*16+g]=q0; qarr[(cb+1)*16+g]=q1; qarr[(cb+2)*16+g]=q2; qarr[(cb+3)*16+g]=q3;
    __syncthreads();
    if (t < 64) {
        float ss = 0.f, qq = 0.f;
        #pragma unroll
        for (int gg = 0; gg < 16; ++gg) { ss += sarr[t*16+gg]; qq += qarr[t*16+gg]; }
        float mu = ss * (1.0f/256.0f);
        float var = qq * (1.0f/256.0f) - mu * mu;
        murs[t] = mu; murs[64 + t] = rsqrtf(var + 1e-5f);
    }
    __syncthreads();
    {
        float m0 = murs[cb], m1 = murs[cb+1], m2 = murs[cb+2], m3 = murs[cb+3];
        float r0 = murs[64+cb], r1 = murs[64+cb+1], r2 = murs[64+cb+2], r3 = murs[64+cb+3];
        int c4 = t & 15;
        #pragma unroll
        for (int r = 0; r < 16; ++r) {
            float4 v = xv[r];
            int px = (t >> 4) + r * 16;
            uint2 o;
            o.x = (u32)f2bf((v.x-m0)*r0) | ((u32)f2bf((v.y-m1)*r1) << 16);
            o.y = (u32)f2bf((v.z-m2)*r2) | ((u32)f2bf((v.w-m3)*r3) << 16);
            *(uint2*)&xs[swz(px, c4 >> 1) + (c4 & 1) * 4] = o;
        }
    }
    int wv = t >> 6, l = t & 63, m = l & 15, qd = l >> 4;
    int px0 = wv * 64;
    const u16* Ws[2] = {Wa, Wb};
    const float* bs[2] = {ba, bbp};
    u16* outs[2] = {oa, obp};
    int hs[2] = {ha, hb};
    for (int ti = 0; ti < 2; ++ti) {
        if (ti) __syncthreads();
        for (int u = t; u < 256; u += 256) {
            int e = u >> 3, c8 = u & 7;
            *(uint4*)&wl[swz(e, c8)] =
                *(const uint4*)(Ws[ti] + (size_t)(hs[ti] * 16 + e) * 64 + c8 * 8);
        }
        __syncthreads();
        f32x4 acc[4][2];
        #pragma unroll
        for (int nt = 0; nt < 2; ++nt) {
            float bb = bs[ti][hs[ti] * 16 + nt * 16 + m];
            #pragma unroll
            for (int mt = 0; mt < 4; ++mt) acc[mt][nt] = {bb, bb, bb, bb};
        }
        #pragma unroll
        for (int ks = 0; ks < 2; ++ks) {
            U8 af[4], bf[2];
            #pragma unroll
            for (int mt = 0; mt < 4; ++mt)
                af[mt].u = *(const uint4*)&xs[swz(px0 + mt*16 + m, ks*4 + qd)];
            #pragma unroll
            for (int nt = 0; nt < 2; ++nt)
                bf[nt].u = *(const uint4*)&wl[swz(nt*16 + m, ks*4 + qd)];
            #pragma unroll
            for (int mt = 0; mt < 4; ++mt)
                #pragma unroll
                for (int nt = 0; nt < 2; ++nt)
                    acc[mt][nt] = __builtin_amdgcn_mfma_f32_16x16x32_bf16(
                        af[mt].b, bf[nt].b, acc[mt][nt], 0, 0, 0);
        }
        u16* epw = ep + wv * 1280;             // 32*(32+8)
        u16* dst0 = outs[ti] + (size_t)n * 8192;
        #pragma unroll
        for (int ch2 = 0; ch2 < 2; ++ch2) {
            if (ch2) CBAR();
            #pragma unroll
            for (int mt = ch2*2; mt < ch2*2+2; ++mt)
                #pragma unroll
                for (int nt = 0; nt < 2; ++nt)
                    #pragma unroll
                    for (int r = 0; r < 4; ++r)
                        epw[((mt&1)*16 + qd*4 + r) * 40 + nt*16 + m] = f2bf(acc[mt][nt][r]);
            CBAR();
            #pragma unroll
            for (int u = l; u < 128; u += 64) {
                int row = u >> 2, c8 = u & 3;
                *(uint4*)(dst0 + (size_t)(px0 + ch2*32 + row) * 32 + c8*8)
                    = *(uint4*)&epw[row * 40 + c8*8];
            }
        }
    }
}

// ---------------- scores via MFMA + softmax (CW=32 slabs) ------------------
__global__ __launch_bounds__(256, 4)
void scores_mfma(const u16* __restrict__ q, const u16* __restrict__ k,
                 int shifted, int hbase, float* __restrict__ A) {
    int w = blockIdx.x, hy = blockIdx.y, t = threadIdx.x;
    int wv = t >> 6, l = t & 63, m = l & 15, qd = l >> 4;
    int n0 = w * 16 + m;
    int ni = shifted ? shift_tok(n0) : n0;
    size_t base = (size_t)ni * 8192 + hy * 16 + (qd & 1) * 8;
    const u16* qrow = q + base;
    const u16* krow = k + base;
    int pxb = wv * 64 + (qd >> 1);
    f32x4 acc = {0.f, 0.f, 0.f, 0.f};
    for (int s = 0; s < 32; ++s) {
        U8 qa, kv;
        qa.u = *(const uint4*)(qrow + (size_t)(pxb + s*2) * 32);
        kv.u = *(const uint4*)(krow + (size_t)(pxb + s*2) * 32);
        acc = __builtin_amdgcn_mfma_f32_16x16x32_bf16(qa.b, kv.b, acc, 0, 0, 0);
    }
    __shared__ float pc[4][256];
    #pragma unroll
    for (int r = 0; r < 4; ++r) pc[wv][l * 4 + r] = acc[r];
    __syncthreads();
    if (wv == 0) {
        float* arow = A + ((size_t)(w * 4 + hbase + hy) * 16) * 16;
        #pragma unroll
        for (int r = 0; r < 4; ++r) {
            float sc = (pc[0][l*4+r] + pc[1][l*4+r] + pc[2][l*4+r] + pc[3][l*4+r])
                     * (1.0f / 1024.0f);
            float mx = sc;
            #pragma unroll
            for (int off = 1; off < 16; off <<= 1) mx = fmaxf(mx, __shfl_xor(mx, off, 16));
            float e = expf(sc - mx);
            float ssum = e;
            #pragma unroll
            for (int off = 1; off < 16; off <<= 1) ssum += __shfl_xor(ssum, off, 16);
            arow[(qd * 4 + r) * 16 + m] = e / ssum;
        }
    }
}

// ---------------- fused A@v + Wo MFMA + residual RMW -----------------------
// block = one (window-view) token; o-tile computed in-block from v slabs.
// XCD swizzle: all 16 token-blocks of a window land on one XCD (%8 heuristic).
__global__ __launch_bounds__(256, 3)
void wo_av(const u16* __restrict__ v1, const u16* __restrict__ v2,
           const float* __restrict__ A,
           const u16* __restrict__ Wo, const float* __restrict__ bo,
           int shifted, float* __restrict__ dres) {
    extern __shared__ char smem[];
    u16* xs = (u16*)smem;               // [256][64] swz: o-tile bf16
    u16* wl = (u16*)(smem + 32768);     // [64][64] swz
    float* As = (float*)(smem + 40960); // [4 heads][16 j]
    int*  nis = (int*)(smem + 41216);   // 16
    int bid = blockIdx.x;
    int qg = bid >> 7, r7 = bid & 127;
    int n = ((qg << 3) + (r7 & 7)) * 16 + (r7 >> 3);
    int t = threadIdx.x;
    int wv = t >> 6, l = t & 63, m = l & 15, qd = l >> 4;
    int px0 = wv * 64;
    int w = n >> 4, i = n & 15;
    int no = shifted ? shift_tok(n) : n;
    if (t < 16) { int nn = w * 16 + t; nis[t] = shifted ? shift_tok(nn) : nn; }
    if (t >= 64 && t < 128) {
        int u = t - 64;
        As[u] = A[(size_t)(w * 4 + (u >> 4)) * 256 + i * 16 + (u & 15)];
    }
    #pragma unroll
    for (int r = 0; r < 2; ++r) {
        int u = t + r * 256;
        int e = u >> 3, c8 = u & 7;
        *(uint4*)&wl[swz(e, c8)] = *(const uint4*)(Wo + e * 64 + c8 * 8);
    }
    __syncthreads();
    // o-tile = A @ v, written into xs (bf16, swizzled)
    #pragma unroll
    for (int r = 0; r < 8; ++r) {
        int idx = r * 256 + t;
        int px = idx >> 3, c8 = idx & 7, h = c8 >> 1;
        float a0=0,a1=0,a2=0,a3=0,a4=0,a5=0,a6=0,a7=0;
        #pragma unroll
        for (int j = 0; j < 16; ++j) {
            const u16* src = (c8 < 4)
                ? (v1 + (size_t)nis[j] * 8192 + px * 32 + c8 * 8)
                : (v2 + (size_t)nis[j] * 8192 + px * 32 + (c8 - 4) * 8);
            uint4 pv = *(const uint4*)src;
            float aw = As[h * 16 + j];
            a0 = fmaf(aw, __uint_as_float(pv.x << 16), a0);
            a1 = fmaf(aw, __uint_as_float(pv.x & 0xFFFF0000u), a1);
            a2 = fmaf(aw, __uint_as_float(pv.y << 16), a2);
            a3 = fmaf(aw, __uint_as_float(pv.y & 0xFFFF0000u), a3);
            a4 = fmaf(aw, __uint_as_float(pv.z << 16), a4);
            a5 = fmaf(aw, __uint_as_float(pv.z & 0xFFFF0000u), a5);
            a6 = fmaf(aw, __uint_as_float(pv.w << 16), a6);
            a7 = fmaf(aw, __uint_as_float(pv.w & 0xFFFF0000u), a7);
        }
        uint4 o;
        o.x = (u32)f2bf(a0) | ((u32)f2bf(a1) << 16);
        o.y = (u32)f2bf(a2) | ((u32)f2bf(a3) << 16);
        o.z = (u32)f2bf(a4) | ((u32)f2bf(a5) << 16);
        o.w = (u32)f2bf(a6) | ((u32)f2bf(a7) << 16);
        *(uint4*)&xs[swz(px, c8)] = o;
    }
    __syncthreads();
    // GEMM: d[no] += Wo · o + bo
    f32x4 acc[4][4];
    #pragma unroll
    for (int nt = 0; nt < 4; ++nt) {
        float bb = bo[nt * 16 + m];
        #pragma unroll
        for (int mt = 0; mt < 4; ++mt) acc[mt][nt] = {bb, bb, bb, bb};
    }
    #pragma unroll
    for (int ks = 0; ks < 2; ++ks) {
        U8 af[4], bf[4];
        #pragma unroll
        for (int mt = 0; mt < 4; ++mt)
            af[mt].u = *(const uint4*)&xs[swz(px0 + mt*16 + m, ks*4 + qd)];
        #pragma unroll
        for (int nt = 0; nt < 4; ++nt)
            bf[nt].u = *(const uint4*)&wl[swz(nt*16 + m, ks*4 + qd)];
        #pragma unroll
        for (int mt = 0; mt < 4; ++mt)
            #pragma unroll
            for (int nt = 0; nt < 4; ++nt)
                acc[mt][nt] = __builtin_amdgcn_mfma_f32_16x16x32_bf16(
                    af[mt].b, bf[nt].b, acc[mt][nt], 0, 0, 0);
    }
    __syncthreads();                     // xs/wl/As dead -> alias eps
    float* eps = (float*)smem + wv * 2304;
    float* dp = dres + (size_t)no * TOKSZ;
    #pragma unroll
    for (int ch2 = 0; ch2 < 2; ++ch2) {
        if (ch2) CBAR();
        #pragma unroll
        for (int mt = ch2*2; mt < ch2*2+2; ++mt)
            #pragma unroll
            for (int nt = 0; nt < 4; ++nt)
                #pragma unroll
                for (int r = 0; r < 4; ++r)
                    eps[((mt&1)*16 + qd*4 + r) * 68 + nt*16 + m] = acc[mt][nt][r];
        CBAR();
        #pragma unroll
        for (int j = 0; j < 8; ++j) {
            int f = l + 64*j; int row = f >> 4, c4 = f & 15;
            float4 dv = *(float4*)&eps[row * 68 + c4 * 4];
            float* gp = &dp[(px0 + ch2*32 + row) * 64 + c4 * 4];
            float4 gv = *(float4*)gp;
            gv.x += dv.x; gv.y += dv.y; gv.z += dv.z; gv.w += dv.w;
            *(float4*)gp = gv;
        }
    }
}

// ---------------- fused norm + MLP + register-residual ---------------------
__global__ __launch_bounds__(256, 3)
void mlp_fused(float* __restrict__ dres,
               const u16* __restrict__ W1, const float* __restrict__ b1,
               const u16* __restrict__ W2, const float* __restrict__ b2) {
    extern __shared__ char smem[];
    u16* xs = (u16*)smem;                      // [256][64] swizzled; xhat then h
    u16* wl = (u16*)(smem + 32768);
    float* sarr = (float*)(smem + 32768);
    float* murs = (float*)(smem + 40960);
    int n = blockIdx.x, t = threadIdx.x;
    int wv = t >> 6, l = t & 63, m = l & 15, qd = l >> 4;
    int px0 = wv * 64;
    int rbase = l >> 4, c4 = l & 15;
    const float4* gin = (const float4*)(dres + (size_t)n * TOKSZ);
    float4 xv[2][8];
    float s0=0,s1=0,s2=0,s3=0,q0=0,q1=0,q2=0,q3=0;
    #pragma unroll
    for (int ch2 = 0; ch2 < 2; ++ch2)
        #pragma unroll
        for (int j = 0; j < 8; ++j) {
            float4 v = gin[(px0 + ch2*32 + rbase + 4*j) * 16 + c4];
            xv[ch2][j] = v;
            s0 += v.x; q0 = fmaf(v.x, v.x, q0);
            s1 += v.y; q1 = fmaf(v.y, v.y, q1);
            s2 += v.z; q2 = fmaf(v.z, v.z, q2);
            s3 += v.w; q3 = fmaf(v.w, v.w, q3);
        }
    int cb = 4 * c4, g = t >> 4;
    sarr[(cb+0)*16+g]=s0; sarr[(cb+1)*16+g]=s1; sarr[(cb+2)*16+g]=s2; sarr[(cb+3)*16+g]=s3;
    float* qarr = sarr + 1024;
    qarr[(cb+0)*16+g]=q0; qarr[(cb+1)*16+g]=q1; qarr[(cb+2)*16+g]=q2; qarr[(cb+3)*16+g]=q3;
    __syncthreads();
    if (t < 64) {
        float ss = 0.f, qq = 0.f;
        #pragma unroll
        for (int gg = 0; gg < 16; ++gg) { ss += sarr[t*16+gg]; qq += qarr[t*16+gg]; }
        float mu = ss * (1.0f/256.0f);
        float var = qq * (1.0f/256.0f) - mu * mu;
        murs[t] = mu; murs[64 + t] = rsqrtf(var + 1e-5f);
    }
    __syncthreads();
    {
        float m0 = murs[cb], m1 = murs[cb+1], m2 = murs[cb+2], m3 = murs[cb+3];
        float r0 = murs[64+cb], r1 = murs[64+cb+1], r2 = murs[64+cb+2], r3 = murs[64+cb+3];
        #pragma unroll
        for (int ch2 = 0; ch2 < 2; ++ch2)
            #pragma unroll
            for (int j = 0; j < 8; ++j) {
                float4 v = xv[ch2][j];
                int row = px0 + ch2*32 + rbase + 4*j;
                uint2 o;
                o.x = (u32)f2bf((v.x-m0)*r0) | ((u32)f2bf((v.y-m1)*r1) << 16);
                o.y = (u32)f2bf((v.z-m2)*r2) | ((u32)f2bf((v.w-m3)*r3) << 16);
                *(uint2*)&xs[swz(row, c4 >> 1) + (c4 & 1) * 4] = o;
            }
    }
    #pragma unroll
    for (int r = 0; r < 2; ++r) {
        int u = t + r * 256;
        int e = u >> 3, c8 = u & 7;
        *(uint4*)&wl[swz(e, c8)] = *(const uint4*)(W1 + e * 64 + c8 * 8);
    }
    __syncthreads();
    f32x4 acc[4][4];
    #pragma unroll
    for (int nt = 0; nt < 4; ++nt) {
        float bb = b1[nt * 16 + m];
        #pragma unroll
        for (int mt = 0; mt < 4; ++mt) acc[mt][nt] = {bb, bb, bb, bb};
    }
    #pragma unroll
    for (int ks = 0; ks < 2; ++ks) {
        U8 af[4], bf[4];
        #pragma unroll
        for (int mt = 0; mt < 4; ++mt)
            af[mt].u = *(const uint4*)&xs[swz(px0 + mt*16 + m, ks*4 + qd)];
        #pragma unroll
        for (int nt = 0; nt < 4; ++nt)
            bf[nt].u = *(const uint4*)&wl[swz(nt*16 + m, ks*4 + qd)];
        #pragma unroll
        for (int mt = 0; mt < 4; ++mt)
            #pragma unroll
            for (int nt = 0; nt < 4; ++nt)
                acc[mt][nt] = __builtin_amdgcn_mfma_f32_16x16x32_bf16(
                    af[mt].b, bf[nt].b, acc[mt][nt], 0, 0, 0);
    }
    __syncthreads();
    #pragma unroll
    for (int nt = 0; nt < 4; ++nt) {
        int ch = nt * 16 + m;
        #pragma unroll
        for (int mt = 0; mt < 4; ++mt)
            #pragma unroll
            for (int r = 0; r < 4; ++r) {
                int R = px0 + mt*16 + qd*4 + r;
                xs[swz(R, ch >> 3) + (ch & 7)] = f2bf(gelu_f(acc[mt][nt][r]));
            }
    }
    #pragma unroll
    for (int r = 0; r < 2; ++r) {
        int u = t + r * 256;
        int e = u >> 3, c8 = u & 7;
        *(uint4*)&wl[swz(e, c8)] = *(const uint4*)(W2 + e * 64 + c8 * 8);
    }
    __syncthreads();
    #pragma unroll
    for (int nt = 0; nt < 4; ++nt) {
        float bb = b2[nt * 16 + m];
        #pragma unroll
        for (int mt = 0; mt < 4; ++mt) acc[mt][nt] = {bb, bb, bb, bb};
    }
    #pragma unroll
    for (int ks = 0; ks < 2; ++ks) {
        U8 af[4], bf[4];
        #pragma unroll
        for (int mt = 0; mt < 4; ++mt)
            af[mt].u = *(const uint4*)&xs[swz(px0 + mt*16 + m, ks*4 + qd)];
        #pragma unroll
        for (int nt = 0; nt < 4; ++nt)
            bf[nt].u = *(const uint4*)&wl[swz(nt*16 + m, ks*4 + qd)];
        #pragma unroll
        for (int mt = 0; mt < 4; ++mt)
            #pragma unroll
            for (int nt = 0; nt < 4; ++nt)
                acc[mt][nt] = __builtin_amdgcn_mfma_f32_16x16x32_bf16(
                    af[mt].b, bf[nt].b, acc[mt][nt], 0, 0, 0);
    }
    __syncthreads();
    float* eps = (float*)smem + wv * 2304;
    float* dp = dres + (size_t)n * TOKSZ;
    #pragma unroll
    for (int ch2 = 0; ch2 < 2; ++ch2) {
        if (ch2) CBAR();
        #pragma unroll
        for (int mt = ch2*2; mt < ch2*2+2; ++mt)
            #pragma unroll
            for (int nt = 0; nt < 4; ++nt)
                #pragma unroll
                for (int r = 0; r < 4; ++r)
                    eps[((mt&1)*16 + qd*4 + r) * 68 + nt*16 + m] = acc[mt][nt][r];
        CBAR();
        #pragma unroll
        for (int j = 0; j < 8; ++j) {
            int f = l + 64*j; int row = f >> 4, cc = f & 15;
            float4 dv = *(float4*)&eps[row * 68 + cc * 4];
            float4 bs = xv[ch2][j];                   // residual from registers
            bs.x += dv.x; bs.y += dv.y; bs.z += dv.z; bs.w += dv.w;
            *(float4*)&dp[(px0 + ch2*32 + row) * 64 + cc * 4] = bs;
        }
    }
}

// ---------------- output MLP via MFMA: 64 -> 128(gelu) -> 1 ----------------
__global__ __launch_bounds__(256, 3)
void out_mfma(const float* __restrict__ d,
              const u16* __restrict__ W1, const float* __restrict__ b1,
              const float* __restrict__ W2, const float* __restrict__ b2,
              void* __restrict__ out, const int* __restrict__ flag) {
    extern __shared__ char smem[];
    u16* xs = (u16*)smem;
    u16* wl = (u16*)(smem + 32768);
    int n = blockIdx.x, t = threadIdx.x;
    int wv = t >> 6, l = t & 63, m = l & 15, qd = l >> 4;
    int px0 = wv * 64;
    const float4* gin = (const float4*)(d + (size_t)n * TOKSZ);
    #pragma unroll
    for (int r = 0; r < 16; ++r) {
        float4 xv = gin[t + r * 256];
        int fi = t + r * 256;
        int px = fi >> 4, c4 = fi & 15;
        uint2 o;
        o.x = (u32)f2bf(xv.x) | ((u32)f2bf(xv.y) << 16);
        o.y = (u32)f2bf(xv.z) | ((u32)f2bf(xv.w) << 16);
        *(uint2*)&xs[swz(px, c4 >> 1) + (c4 & 1) * 4] = o;
    }
    float val[4][4];
    #pragma unroll
    for (int mt = 0; mt < 4; ++mt)
        #pragma unroll
        for (int r = 0; r < 4; ++r) val[mt][r] = 0.f;
    for (int nh = 0; nh < 2; ++nh) {
        if (nh) __syncthreads();
        #pragma unroll
        for (int r = 0; r < 2; ++r) {
            int u = t + r * 256;
            int e = u >> 3, c8 = u & 7;
            *(uint4*)&wl[swz(e, c8)] = *(const uint4*)(W1 + (size_t)nh * 4096 + e * 64 + c8 * 8);
        }
        __syncthreads();
        f32x4 acc[4][4];
        #pragma unroll
        for (int nt = 0; nt < 4; ++nt) {
            float bb = b1[nh * 64 + nt * 16 + m];
            #pragma unroll
            for (int mt = 0; mt < 4; ++mt) acc[mt][nt] = {bb, bb, bb, bb};
        }
        #pragma unroll
        for (int ks = 0; ks < 2; ++ks) {
            U8 af[4], bf[4];
            #pragma unroll
            for (int mt = 0; mt < 4; ++mt)
                af[mt].u = *(const uint4*)&xs[swz(px0 + mt*16 + m, ks*4 + qd)];
            #pragma unroll
            for (int nt = 0; nt < 4; ++nt)
                bf[nt].u = *(const uint4*)&wl[swz(nt*16 + m, ks*4 + qd)];
            #pragma unroll
            for (int mt = 0; mt < 4; ++mt)
                #pragma unroll
                for (int nt = 0; nt < 4; ++nt)
                    acc[mt][nt] = __builtin_amdgcn_mfma_f32_16x16x32_bf16(
                        af[mt].b, bf[nt].b, acc[mt][nt], 0, 0, 0);
        }
        float w2v[4];
        #pragma unroll
        for (int nt = 0; nt < 4; ++nt) w2v[nt] = W2[nh * 64 + nt * 16 + m];
        #pragma unroll
        for (int mt = 0; mt < 4; ++mt)
            #pragma unroll
            for (int r = 0; r < 4; ++r) {
                float p = 0.f;
                #pragma unroll
                for (int nt = 0; nt < 4; ++nt)
                    p = fmaf(gelu_f(acc[mt][nt][r]), w2v[nt], p);
                val[mt][r] += p;
            }
    }
    __syncthreads();
    float* red = (float*)smem;                 // [256][17]
    #pragma unroll
    for (int mt = 0; mt < 4; ++mt)
        #pragma unroll
        for (int r = 0; r < 4; ++r)
            red[(px0 + mt*16 + qd*4 + r) * 17 + m] = val[mt][r];
    __syncthreads();
    float a = b2[0];
    #pragma unroll
    for (int j = 0; j < 16; ++j) a += red[t * 17 + j];
    int w = n >> 4, s = n & 15;
    int b = w >> 4, wy = (w >> 2) & 3, wx = w & 3;
    int ty = s >> 2, tx = s & 3;
    int y = ((wy << 2) + ty) * 16 + (t >> 4);
    int x = ((wx << 2) + tx) * 16 + (t & 15);
    size_t oi = (size_t)b * 65536 + (size_t)y * 256 + (size_t)x;
    if (*flag) ((float*)out)[oi] = a;
    else       ((u16*)out)[oi] = f2bf(a);
}

// ---------------- host launch ----------------------------------------------
extern "C" void kernel_launch(void* const* d_in, const int* in_sizes, int n_in,
                              void* d_out, int out_size, void* d_ws, size_t ws_size,
                              hipStream_t stream) {
    (void)n_in; (void)out_size; (void)ws_size;
    const int* pdsy = (const int*)d_in[21];
    const int* pdsx = (const int*)d_in[22];

    // proven 235.65 MB layout (R8)
    char* wsb = (char*)d_ws;
    float* bufd = (float*)wsb;
    u16* qb = (u16*)(wsb + 134217728ull);
    u16* kb = (u16*)(wsb + 167772160ull);
    u16* vb = (u16*)(wsb + 201326592ull);
    float* A     = (float*)(wsb + 234881024ull);
    float* wbufA = (float*)(wsb + 235405312ull);
    u16* wbuf16  = (u16*)(wsb + 235416064ull);
    int* flag    = (int*)(wsb + 235650816ull);

    const int f32set[12] = {1, 2, 4, 6, 8, 10, 12, 14, 16, 18, 19, 20};
    WArgs wa;
    int off16[NWT + 1]; off16[0] = 0;
    int c32[NWT + 1];
    int fo = 0;
    for (int i = 0; i < NWT; ++i) {
        int di = i + 1;
        wa.src[i] = d_in[di];
        off16[i + 1] = off16[i] + in_sizes[di];
        wa.off16[i] = off16[i];
        int isf = 0;
        for (int j = 0; j < 12; ++j) if (f32set[j] == di) isf = 1;
        wa.f32o[i] = isf ? fo : -1;
        c32[di] = isf ? fo : -1;
        if (isf) fo += in_sizes[di];
    }
    wa.off16[NWT] = off16[NWT];

    detect_kernel<<<1, 64, 0, stream>>>((const u16*)d_in[1], flag);
    cvt_weights<<<(off16[NWT] + 255) / 256, 256, 0, stream>>>(wa, flag, wbufA, wbuf16);

    const float* f_inpW1 = wbufA + c32[1];
    const float* f_inpb1 = wbufA + c32[2];
    const float* f_inpb2 = wbufA + c32[4];
    const float* f_bq  = wbufA + c32[6];
    const float* f_bk  = wbufA + c32[8];
    const float* f_bv  = wbufA + c32[10];
    const float* f_bo  = wbufA + c32[12];
    const float* f_mb1 = wbufA + c32[14];
    const float* f_mb2 = wbufA + c32[16];
    const float* f_ob1 = wbufA + c32[18];
    const float* f_oW2 = wbufA + c32[19];
    const float* f_ob2 = wbufA + c32[20];
    const u16* h_inpW2 = wbuf16 + off16[2];
    const u16* h_Wq  = wbuf16 + off16[4];
    const u16* h_Wk  = wbuf16 + off16[6];
    const u16* h_Wv  = wbuf16 + off16[8];
    const u16* h_Wo  = wbuf16 + off16[10];
    const u16* h_mW1 = wbuf16 + off16[12];
    const u16* h_mW2 = wbuf16 + off16[14];
    const u16* h_oW1 = wbuf16 + off16[16];

    embed_mfma<<<NTOK, 256, 40960, stream>>>(d_in[0], flag, f_inpW1, f_inpb1,
                                             h_inpW2, f_inpb2, pdsy, pdsx, bufd);

    for (int l = 0; l < 4; ++l) {
        int sh = l & 1;
        const u16* Wql = h_Wq + l * 4096;  const float* bql = f_bq + l * 64;
        const u16* Wkl = h_Wk + l * 4096;  const float* bkl = f_bk + l * 64;
        const u16* Wvl = h_Wv + l * 4096;  const float* bvl = f_bv + l * 64;
        const u16* Wol = h_Wo + l * 4096;  const float* bol = f_bo + l * 64;
        const u16* W1l = h_mW1 + l * 4096; const float* b1l = f_mb1 + l * 64;
        const u16* W2l = h_mW2 + l * 4096; const float* b2l = f_mb2 + l * 64;

        proj_kernel<<<NTOK, 256, 51712, stream>>>(bufd, Wql, bql, Wkl, bkl, 0, 0, qb, kb);
        scores_mfma<<<dim3(128, 2), 256, 0, stream>>>(qb, kb, sh, 0, A);
        proj_kernel<<<NTOK, 256, 51712, stream>>>(bufd, Wql, bql, Wkl, bkl, 2, 2, qb, kb);
        scores_mfma<<<dim3(128, 2), 256, 0, stream>>>(qb, kb, sh, 2, A);
        proj_kernel<<<NTOK, 256, 51712, stream>>>(bufd, Wvl, bvl, Wvl, bvl, 0, 2, vb, kb);
        wo_av<<<NTOK, 256, 41280, stream>>>(vb, kb, A, Wol, bol, sh, bufd);
        mlp_fused<<<NTOK, 256, 41472, stream>>>(bufd, W1l, b1l, W2l, b2l);
    }

    out_mfma<<<NTOK, 256, 40960, stream>>>(bufd, h_oW1, f_ob1, f_oW2, f_ob2,
                                           d_out, flag);
}